// Round 1
// baseline (791.930 us; speedup 1.0000x reference)
//
#include <hip/hip_runtime.h>
#include <math.h>

#define N_NODES 50000
#define N_EDGES 800000
#define KINC 16
#define DIM 128
#define NH 8
#define DHD 16
#define QSCALE 0.08838834764831845f
#define LEPS 1e-5f

__device__ __forceinline__ float gelu_f(float x) {
    const float c = 0.7978845608028654f; // sqrt(2/pi)
    float x3 = x * x * x;
    return 0.5f * x * (1.f + tanhf(c * (x + 0.044715f * x3)));
}

// ---------------- Kernel 1: LN(triplet_h) @ qkv_w + b  -> qkv (q pre-scaled) ----
// 32 rows/block, 256 threads. xs transposed [k][row] pad 33. W staged 16-k chunks.
__global__ __launch_bounds__(256) void k_ln_qkv(
    const float* __restrict__ th, const float* __restrict__ g1, const float* __restrict__ b1,
    const float* __restrict__ w, const float* __restrict__ bias, float* __restrict__ qkv)
{
    __shared__ float xs[128][33];
    __shared__ float wsh[16][384];
    const int tid = threadIdx.x;
    const int lane = tid & 63;
    const int wid = tid >> 6;
    const int g0 = blockIdx.x * 32;

    float ga = g1[lane], gb = g1[lane + 64];
    float ba = b1[lane], bb = b1[lane + 64];

    // Stage A: LayerNorm 8 rows per wave, store transposed (stride 33: conflict-free)
    for (int rr = 0; rr < 8; ++rr) {
        int r = wid * 8 + rr;
        int grow = g0 + r;
        float x0 = 0.f, x1 = 0.f;
        if (grow < N_NODES) {
            x0 = th[(size_t)grow * 128 + lane];
            x1 = th[(size_t)grow * 128 + 64 + lane];
        }
        float s1 = x0 + x1, s2 = x0 * x0 + x1 * x1;
        #pragma unroll
        for (int off = 32; off; off >>= 1) {
            s1 += __shfl_xor(s1, off);
            s2 += __shfl_xor(s2, off);
        }
        float m = s1 * (1.f / 128.f);
        float v = s2 * (1.f / 128.f) - m * m;
        float rs = rsqrtf(v + LEPS);
        xs[lane][r]      = (x0 - m) * rs * ga + ba;
        xs[lane + 64][r] = (x1 - m) * rs * gb + bb;
    }
    __syncthreads();

    const int tc = tid & 63;
    const int tr = tid >> 6;
    const int r0 = tr * 8;
    float acc[8][6];
    #pragma unroll
    for (int i = 0; i < 8; i++)
        #pragma unroll
        for (int c = 0; c < 6; c++) acc[i][c] = 0.f;

    for (int kc = 0; kc < 128; kc += 16) {
        // stage 16x384 chunk of W (flat copy, coalesced)
        #pragma unroll
        for (int t = 0; t < 24; ++t) {
            int idx = tid + 256 * t;
            ((float*)wsh)[idx] = w[kc * 384 + idx];
        }
        __syncthreads();
        #pragma unroll 4
        for (int kk = 0; kk < 16; ++kk) {
            float a[8];
            #pragma unroll
            for (int i = 0; i < 8; i++) a[i] = xs[kc + kk][r0 + i];  // broadcast
            #pragma unroll
            for (int c = 0; c < 6; c++) {
                float bv = wsh[kk][tc + 64 * c];
                #pragma unroll
                for (int i = 0; i < 8; i++) acc[i][c] = fmaf(a[i], bv, acc[i][c]);
            }
        }
        __syncthreads();
    }
    // epilogue: add bias, scale q part, store
    #pragma unroll
    for (int i = 0; i < 8; i++) {
        int grow = g0 + r0 + i;
        if (grow >= N_NODES) continue;
        #pragma unroll
        for (int c = 0; c < 6; c++) {
            int j = tc + 64 * c;
            float vv = acc[i][c] + bias[j];
            if (j < 128) vv *= QSCALE;  // q part
            qkv[(size_t)grow * 384 + j] = vv;
        }
    }
}

// ---------------- Kernel 2: per-edge scores = dot(q[src],k[dst]) + edge_bias ----
__global__ __launch_bounds__(256) void k_edge_scores(
    const float* __restrict__ qkv, const int* __restrict__ src, const int* __restrict__ dst,
    const float* __restrict__ eb, float* __restrict__ scores)
{
    int t = blockIdx.x * 256 + threadIdx.x;
    int e = t >> 3, h = t & 7;
    if (e >= N_EDGES) return;
    int s = src[e], d = dst[e];
    const float4* qp = (const float4*)(qkv + (size_t)s * 384 + h * 16);
    const float4* kp = (const float4*)(qkv + (size_t)d * 384 + 128 + h * 16);
    float acc = 0.f;
    #pragma unroll
    for (int i = 0; i < 4; i++) {
        float4 a = qp[i], b = kp[i];
        acc += a.x * b.x + a.y * b.y + a.z * b.z + a.w * b.w;
    }
    scores[(size_t)e * 8 + h] = acc + eb[(size_t)e * 8 + h];
}

// ---------------- Kernel 3: per-node softmax over K=16 incoming, aggregate v ----
__global__ __launch_bounds__(128) void k_agg(
    const float* __restrict__ qkv, const float* __restrict__ scores,
    const int* __restrict__ inc_idx, const int* __restrict__ src,
    float* __restrict__ outw)
{
    __shared__ int es[16];
    __shared__ int ss[16];
    __shared__ float sc[16][8];
    int n = blockIdx.x;
    int j = threadIdx.x;   // 0..127 = h*16+dh
    int h = j >> 4;
    if (j < 16) {
        int e = inc_idx[(size_t)n * 16 + j];
        if (e < 0) e = 0;
        es[j] = e;
        ss[j] = src[e];
    }
    __syncthreads();
    {
        int k = j >> 3, hh = j & 7;
        sc[k][hh] = scores[(size_t)es[k] * 8 + hh];
    }
    __syncthreads();
    float m = -1e30f;
    #pragma unroll
    for (int k = 0; k < 16; k++) m = fmaxf(m, sc[k][h]);
    float p[16];
    float sum = 0.f;
    #pragma unroll
    for (int k = 0; k < 16; k++) { p[k] = __expf(sc[k][h] - m); sum += p[k]; }
    float inv = 1.f / sum;
    float acc = 0.f;
    #pragma unroll
    for (int k = 0; k < 16; k++) acc += p[k] * qkv[(size_t)ss[k] * 384 + 256 + j];
    outw[(size_t)n * 128 + j] = acc * inv;
}

// ---------------- Kernel 4: x2 = th + out@res_in_w + b; LN; FFN; out = x2 + y ---
// 32 rows/block, 256 threads. tc=tid&63 (cols tc, tc+64), tr=tid>>6 (rows tr*8..+7)
__global__ __launch_bounds__(256) void k_ffn(
    const float* __restrict__ th, const float* __restrict__ outw,
    const float* __restrict__ riw, const float* __restrict__ rib,
    const float* __restrict__ rlg, const float* __restrict__ rlb,
    const float* __restrict__ fiw, const float* __restrict__ fib,
    const float* __restrict__ fow, const float* __restrict__ fob,
    float* __restrict__ dout)
{
    __shared__ float os[128][33];   // out^T tile; reused as hs (gelu h1^T) in FFN
    __shared__ float ys[128][33];   // LN(x2)^T
    __shared__ float wbuf[32][128];
    auto hs = os;
    const int tid = threadIdx.x;
    const int g0 = blockIdx.x * 32;
    const int tc = tid & 63, tr = tid >> 6, r0 = tr * 8;

    // load out tile transposed (stride 33 store: conflict-free)
    #pragma unroll
    for (int t = 0; t < 16; ++t) {
        int idx = tid + 256 * t;      // 0..4095
        int r = idx >> 7, j = idx & 127;
        int grow = g0 + r;
        os[j][r] = (grow < N_NODES) ? outw[(size_t)grow * 128 + j] : 0.f;
    }
    __syncthreads();

    // ---- res_in GEMM -> x2 (in registers) ----
    float x2[8][2];
    #pragma unroll
    for (int i = 0; i < 8; i++) { x2[i][0] = 0.f; x2[i][1] = 0.f; }
    for (int kc = 0; kc < 128; kc += 32) {
        #pragma unroll
        for (int t = 0; t < 16; ++t) {
            int idx = tid + 256 * t;
            ((float*)wbuf)[idx] = riw[kc * 128 + idx];
        }
        __syncthreads();
        #pragma unroll 4
        for (int kk = 0; kk < 32; ++kk) {
            float a[8];
            #pragma unroll
            for (int i = 0; i < 8; i++) a[i] = os[kc + kk][r0 + i];
            float b0 = wbuf[kk][tc], b1 = wbuf[kk][tc + 64];
            #pragma unroll
            for (int i = 0; i < 8; i++) {
                x2[i][0] = fmaf(a[i], b0, x2[i][0]);
                x2[i][1] = fmaf(a[i], b1, x2[i][1]);
            }
        }
        __syncthreads();
    }
    {
        float bi0 = rib[tc], bi1 = rib[tc + 64];
        #pragma unroll
        for (int i = 0; i < 8; i++) {
            int grow = g0 + r0 + i;
            if (grow < N_NODES) {
                x2[i][0] += bi0 + th[(size_t)grow * 128 + tc];
                x2[i][1] += bi1 + th[(size_t)grow * 128 + tc + 64];
            } else { x2[i][0] = 0.f; x2[i][1] = 0.f; }
        }
    }
    // ---- LN(x2) -> ys (wave = one tr group, owns rows r0..r0+7) ----
    {
        float lg0 = rlg[tc], lg1 = rlg[tc + 64], lb0 = rlb[tc], lb1 = rlb[tc + 64];
        #pragma unroll
        for (int i = 0; i < 8; i++) {
            float s1 = x2[i][0] + x2[i][1];
            float s2 = x2[i][0] * x2[i][0] + x2[i][1] * x2[i][1];
            #pragma unroll
            for (int off = 32; off; off >>= 1) {
                s1 += __shfl_xor(s1, off);
                s2 += __shfl_xor(s2, off);
            }
            float m = s1 * (1.f / 128.f);
            float v = s2 * (1.f / 128.f) - m * m;
            float rs = rsqrtf(v + LEPS);
            ys[tc][r0 + i]      = (x2[i][0] - m) * rs * lg0 + lb0;
            ys[tc + 64][r0 + i] = (x2[i][1] - m) * rs * lg1 + lb1;
        }
    }
    __syncthreads();

    // ---- FFN: for each 128-wide hidden chunk: h1 = gelu(ys@fiw_c + b); y2 += h1@fow_c
    float y2[8][2];
    #pragma unroll
    for (int i = 0; i < 8; i++) { y2[i][0] = 0.f; y2[i][1] = 0.f; }
    for (int c4 = 0; c4 < 4; c4++) {
        float h1[8][2];
        #pragma unroll
        for (int i = 0; i < 8; i++) { h1[i][0] = 0.f; h1[i][1] = 0.f; }
        for (int kc = 0; kc < 128; kc += 32) {
            __syncthreads();   // protect wbuf from previous readers
            #pragma unroll
            for (int t = 0; t < 16; ++t) {
                int idx = tid + 256 * t;
                int kk = idx >> 7, j = idx & 127;
                wbuf[kk][j] = fiw[(size_t)(kc + kk) * 512 + c4 * 128 + j];
            }
            __syncthreads();
            #pragma unroll 4
            for (int kk = 0; kk < 32; ++kk) {
                float a[8];
                #pragma unroll
                for (int i = 0; i < 8; i++) a[i] = ys[kc + kk][r0 + i];
                float b0 = wbuf[kk][tc], b1 = wbuf[kk][tc + 64];
                #pragma unroll
                for (int i = 0; i < 8; i++) {
                    h1[i][0] = fmaf(a[i], b0, h1[i][0]);
                    h1[i][1] = fmaf(a[i], b1, h1[i][1]);
                }
            }
        }
        __syncthreads();   // everyone done with GEMM1 (reads of wbuf) before hs write
        {
            float fb0 = fib[c4 * 128 + tc], fb1 = fib[c4 * 128 + tc + 64];
            #pragma unroll
            for (int i = 0; i < 8; i++) {
                hs[tc][r0 + i]      = gelu_f(h1[i][0] + fb0);
                hs[tc + 64][r0 + i] = gelu_f(h1[i][1] + fb1);
            }
        }
        __syncthreads();
        for (int kc = 0; kc < 128; kc += 32) {
            #pragma unroll
            for (int t = 0; t < 16; ++t) {
                int idx = tid + 256 * t;
                ((float*)wbuf)[idx] = fow[(size_t)(c4 * 128 + kc) * 128 + idx];
            }
            __syncthreads();
            #pragma unroll 4
            for (int kk = 0; kk < 32; ++kk) {
                float a[8];
                #pragma unroll
                for (int i = 0; i < 8; i++) a[i] = hs[kc + kk][r0 + i];
                float b0 = wbuf[kk][tc], b1 = wbuf[kk][tc + 64];
                #pragma unroll
                for (int i = 0; i < 8; i++) {
                    y2[i][0] = fmaf(a[i], b0, y2[i][0]);
                    y2[i][1] = fmaf(a[i], b1, y2[i][1]);
                }
            }
            __syncthreads();
        }
    }
    // ---- final: out = x2 + (y2 + fob) ----
    {
        float ob0 = fob[tc], ob1 = fob[tc + 64];
        #pragma unroll
        for (int i = 0; i < 8; i++) {
            int grow = g0 + r0 + i;
            if (grow < N_NODES) {
                dout[(size_t)grow * 128 + tc]      = x2[i][0] + y2[i][0] + ob0;
                dout[(size_t)grow * 128 + tc + 64] = x2[i][1] + y2[i][1] + ob1;
            }
        }
    }
}

extern "C" void kernel_launch(void* const* d_in, const int* in_sizes, int n_in,
                              void* d_out, int out_size, void* d_ws, size_t ws_size,
                              hipStream_t stream)
{
    const float* th    = (const float*)d_in[0];
    const int*   src   = (const int*)d_in[2];
    const int*   dst   = (const int*)d_in[3];
    const float* ebias = (const float*)d_in[4];
    const int*   inc   = (const int*)d_in[6];
    const float* ln1g  = (const float*)d_in[8];
    const float* ln1b  = (const float*)d_in[9];
    const float* qkvw  = (const float*)d_in[10];
    const float* qkvb  = (const float*)d_in[11];
    const float* riw   = (const float*)d_in[12];
    const float* rib   = (const float*)d_in[13];
    const float* rlg   = (const float*)d_in[14];
    const float* rlb   = (const float*)d_in[15];
    const float* fiw   = (const float*)d_in[16];
    const float* fib   = (const float*)d_in[17];
    const float* fow   = (const float*)d_in[18];
    const float* fob   = (const float*)d_in[19];

    float* qkv    = (float*)d_ws;                       // N*384
    float* scores = qkv + (size_t)N_NODES * 384;        // E*8
    float* outw   = scores + (size_t)N_EDGES * 8;       // N*128
    float* dout   = (float*)d_out;

    k_ln_qkv<<<(N_NODES + 31) / 32, 256, 0, stream>>>(th, ln1g, ln1b, qkvw, qkvb, qkv);
    k_edge_scores<<<(N_EDGES * 8 + 255) / 256, 256, 0, stream>>>(qkv, src, dst, ebias, scores);
    k_agg<<<N_NODES, 128, 0, stream>>>(qkv, scores, inc, src, outw);
    k_ffn<<<(N_NODES + 31) / 32, 256, 0, stream>>>(th, outw, riw, rib, rlg, rlb,
                                                   fiw, fib, fow, fob, dout);
}

// Round 2
// 452.778 us; speedup vs baseline: 1.7490x; 1.7490x over previous
//
#include <hip/hip_runtime.h>
#include <math.h>

#define N_NODES 50000
#define N_EDGES 800000
#define QSCALE 0.08838834764831845f
#define LEPS 1e-5f

typedef unsigned short ushort_t;
typedef short bf16x8 __attribute__((ext_vector_type(8)));
typedef float f32x4 __attribute__((ext_vector_type(4)));

__device__ __forceinline__ ushort_t f2b(float f) {
    unsigned int u = __float_as_uint(f);
    u += 0x7FFF + ((u >> 16) & 1);   // RNE
    return (ushort_t)(u >> 16);
}
__device__ __forceinline__ float b2f(ushort_t v) {
    return __uint_as_float(((unsigned int)v) << 16);
}
__device__ __forceinline__ float gelu_f(float x) {
    const float c = 0.7978845608028654f; // sqrt(2/pi)
    float x3 = x * x * x;
    return 0.5f * x * (1.f + tanhf(c * (x + 0.044715f * x3)));
}

// ------------- Prep: transpose+convert weights to bf16 W^T[n][k] -------------
__global__ __launch_bounds__(256) void k_prep(
    const float* __restrict__ qkvw, const float* __restrict__ riw,
    const float* __restrict__ fiw,  const float* __restrict__ fow,
    ushort_t* __restrict__ qkvwT, ushort_t* __restrict__ riwT,
    ushort_t* __restrict__ fiwT,  ushort_t* __restrict__ fowT)
{
    int i = blockIdx.x * 256 + threadIdx.x;
    if (i < 384 * 128) { int n = i >> 7, k = i & 127; qkvwT[i] = f2b(qkvw[k * 384 + n]); return; }
    i -= 384 * 128;
    if (i < 128 * 128) { int n = i >> 7, k = i & 127; riwT[i] = f2b(riw[k * 128 + n]); return; }
    i -= 128 * 128;
    if (i < 512 * 128) { int n = i >> 7, k = i & 127; fiwT[i] = f2b(fiw[k * 512 + n]); return; }
    i -= 512 * 128;
    if (i < 128 * 512) { int n = i >> 9, k = i & 511; fowT[i] = f2b(fow[k * 128 + n]); return; }
}

// ------------- K1: LN(triplet_h) @ qkv_w + b -> qkv bf16 (q pre-scaled) ------
// 64 rows/block, 256 thr (4 waves x 16 rows). MFMA 16x16x32 bf16, K=128.
__global__ __launch_bounds__(256) void k1_ln_qkv(
    const float* __restrict__ th, const float* __restrict__ g1, const float* __restrict__ b1,
    const ushort_t* __restrict__ wT, const float* __restrict__ bias, ushort_t* __restrict__ qkvb)
{
    __shared__ ushort_t xs[64][136];   // bf16 LN(x), stride 272B: 16B-aligned rows
    const int tid = threadIdx.x, lane = tid & 63, w = tid >> 6;
    const int g0 = blockIdx.x * 64;

    float ga = g1[lane], gb = g1[lane + 64];
    float ba = b1[lane], bb = b1[lane + 64];
    for (int rr = 0; rr < 16; ++rr) {
        int r = w * 16 + rr, grow = g0 + r;
        float x0 = 0.f, x1 = 0.f;
        if (grow < N_NODES) {
            x0 = th[(size_t)grow * 128 + lane];
            x1 = th[(size_t)grow * 128 + 64 + lane];
        }
        float s1 = x0 + x1, s2 = x0 * x0 + x1 * x1;
        #pragma unroll
        for (int off = 32; off; off >>= 1) { s1 += __shfl_xor(s1, off); s2 += __shfl_xor(s2, off); }
        float m = s1 * (1.f / 128.f);
        float v = s2 * (1.f / 128.f) - m * m;
        float rs = rsqrtf(v + LEPS);
        xs[r][lane]      = f2b((x0 - m) * rs * ga + ba);
        xs[r][lane + 64] = f2b((x1 - m) * rs * gb + bb);
    }
    __syncthreads();

    const int q = lane >> 4, ml = lane & 15;
    bf16x8 a[4];
    #pragma unroll
    for (int kc = 0; kc < 4; ++kc)
        a[kc] = *(const bf16x8*)&xs[w * 16 + ml][kc * 32 + q * 8];

    const int rbase = g0 + w * 16 + q * 4;
    for (int t = 0; t < 24; ++t) {
        f32x4 acc = {0.f, 0.f, 0.f, 0.f};
        const ushort_t* bp = wT + (size_t)(t * 16 + ml) * 128 + q * 8;
        #pragma unroll
        for (int kc = 0; kc < 4; ++kc)
            acc = __builtin_amdgcn_mfma_f32_16x16x32_bf16(a[kc], *(const bf16x8*)(bp + kc * 32), acc, 0, 0, 0);
        float bs = bias[t * 16 + ml];
        float sc = (t < 8) ? QSCALE : 1.f;
        #pragma unroll
        for (int r = 0; r < 4; ++r) {
            int grow = rbase + r;
            if (grow < N_NODES)
                qkvb[(size_t)grow * 384 + t * 16 + ml] = f2b((acc[r] + bs) * sc);
        }
    }
}

// ------------- K2: per-edge scores = dot(q[src],k[dst]) + edge_bias ----------
__global__ __launch_bounds__(256) void k2_edge_scores(
    const ushort_t* __restrict__ qkvb, const int* __restrict__ src, const int* __restrict__ dst,
    const float* __restrict__ eb, float* __restrict__ scores)
{
    int t = blockIdx.x * 256 + threadIdx.x;
    int e = t >> 3, h = t & 7;
    if (e >= N_EDGES) return;
    int s = src[e], d = dst[e];
    const uint4* qp = (const uint4*)(qkvb + (size_t)s * 384 + h * 16);
    const uint4* kp = (const uint4*)(qkvb + (size_t)d * 384 + 128 + h * 16);
    float acc = 0.f;
    #pragma unroll
    for (int i = 0; i < 2; ++i) {
        uint4 qa = qp[i], ka = kp[i];
        const unsigned int* qu = (const unsigned int*)&qa;
        const unsigned int* ku = (const unsigned int*)&ka;
        #pragma unroll
        for (int j = 0; j < 4; ++j) {
            float q0 = __uint_as_float(qu[j] << 16);
            float q1 = __uint_as_float(qu[j] & 0xffff0000u);
            float k0 = __uint_as_float(ku[j] << 16);
            float k1 = __uint_as_float(ku[j] & 0xffff0000u);
            acc = fmaf(q0, k0, acc);
            acc = fmaf(q1, k1, acc);
        }
    }
    scores[t] = acc + eb[t];
}

// ------------- K3: per-node softmax over K=16 incoming, aggregate v ----------
__global__ __launch_bounds__(128) void k3_agg(
    const ushort_t* __restrict__ qkvb, const float* __restrict__ scores,
    const int* __restrict__ inc_idx, const int* __restrict__ src,
    ushort_t* __restrict__ outw)
{
    __shared__ int es[16];
    __shared__ int ss[16];
    __shared__ float sc[16][8];
    int n = blockIdx.x;
    int j = threadIdx.x;   // 0..127 = h*16+dh
    int h = j >> 4;
    if (j < 16) {
        int e = inc_idx[(size_t)n * 16 + j];
        if (e < 0) e = 0;
        es[j] = e;
        ss[j] = src[e];
    }
    __syncthreads();
    {
        int k = j >> 3, hh = j & 7;
        sc[k][hh] = scores[(size_t)es[k] * 8 + hh];
    }
    __syncthreads();
    float m = -1e30f;
    #pragma unroll
    for (int k = 0; k < 16; k++) m = fmaxf(m, sc[k][h]);
    float p[16];
    float sum = 0.f;
    #pragma unroll
    for (int k = 0; k < 16; k++) { p[k] = __expf(sc[k][h] - m); sum += p[k]; }
    float inv = 1.f / sum;
    float acc = 0.f;
    #pragma unroll
    for (int k = 0; k < 16; k++) acc += p[k] * b2f(qkvb[(size_t)ss[k] * 384 + 256 + j]);
    outw[(size_t)n * 128 + j] = f2b(acc * inv);
}

// ------------- K4: x2 = th + out@riw + rib; LN; FFN(gelu); out = x2 + y ------
// 64 rows/block, 256 thr (4 waves x 16 rows). All GEMMs via MFMA 16x16x32 bf16.
__global__ __launch_bounds__(256) void k4_ffn(
    const float* __restrict__ th, const ushort_t* __restrict__ outw,
    const ushort_t* __restrict__ riwT, const float* __restrict__ rib,
    const float* __restrict__ rlg, const float* __restrict__ rlb,
    const ushort_t* __restrict__ fiwT, const float* __restrict__ fib,
    const ushort_t* __restrict__ fowT, const float* __restrict__ fob,
    float* __restrict__ dout)
{
    __shared__ ushort_t xs[64][136];
    __shared__ ushort_t ys[64][136];
    __shared__ ushort_t hs[64][136];
    const int tid = threadIdx.x, lane = tid & 63, w = tid >> 6;
    const int g0 = blockIdx.x * 64;

    // phase 1: stage 'out' tile as bf16
    #pragma unroll
    for (int t = 0; t < 8; ++t) {
        int idx = tid + 256 * t;           // 2048 uint2 chunks
        int r = idx >> 5, c = (idx & 31) * 4;
        int grow = g0 + r;
        uint2 vv = make_uint2(0u, 0u);
        if (grow < N_NODES) vv = *(const uint2*)(outw + (size_t)grow * 128 + c);
        *(uint2*)&xs[r][c] = vv;
    }
    __syncthreads();

    const int q = lane >> 4, ml = lane & 15;
    const int rloc = w * 16 + q * 4;       // this lane's first output row (local)

    bf16x8 a[4];
    #pragma unroll
    for (int kc = 0; kc < 4; ++kc)
        a[kc] = *(const bf16x8*)&xs[w * 16 + ml][kc * 32 + q * 8];

    // GEMM1: x2 = out @ riw + rib + th
    f32x4 x2[8];
    #pragma unroll
    for (int t = 0; t < 8; ++t) {
        f32x4 acc = {0.f, 0.f, 0.f, 0.f};
        const ushort_t* bp = riwT + (size_t)(t * 16 + ml) * 128 + q * 8;
        #pragma unroll
        for (int kc = 0; kc < 4; ++kc)
            acc = __builtin_amdgcn_mfma_f32_16x16x32_bf16(a[kc], *(const bf16x8*)(bp + kc * 32), acc, 0, 0, 0);
        x2[t] = acc;
    }
    #pragma unroll
    for (int t = 0; t < 8; ++t) {
        float bb = rib[t * 16 + ml];
        #pragma unroll
        for (int r = 0; r < 4; ++r) {
            int grow = g0 + rloc + r;
            float tv = (grow < N_NODES) ? th[(size_t)grow * 128 + t * 16 + ml] : 0.f;
            x2[t][r] += bb + tv;
        }
    }

    // LN(x2) -> ys (bf16). Row spread over 16 lanes sharing q (8 cols each).
    {
        float rg[8], rbv[8];
        #pragma unroll
        for (int t = 0; t < 8; ++t) { rg[t] = rlg[t * 16 + ml]; rbv[t] = rlb[t * 16 + ml]; }
        #pragma unroll
        for (int r = 0; r < 4; ++r) {
            float s1 = 0.f, s2 = 0.f;
            #pragma unroll
            for (int t = 0; t < 8; ++t) { float v = x2[t][r]; s1 += v; s2 += v * v; }
            #pragma unroll
            for (int off = 1; off < 16; off <<= 1) { s1 += __shfl_xor(s1, off); s2 += __shfl_xor(s2, off); }
            float m = s1 * (1.f / 128.f);
            float v = s2 * (1.f / 128.f) - m * m;
            float rs = rsqrtf(v + LEPS);
            #pragma unroll
            for (int t = 0; t < 8; ++t)
                ys[rloc + r][t * 16 + ml] = f2b((x2[t][r] - m) * rs * rg[t] + rbv[t]);
        }
    }
    __syncthreads();

    bf16x8 a2[4];
    #pragma unroll
    for (int kc = 0; kc < 4; ++kc)
        a2[kc] = *(const bf16x8*)&ys[w * 16 + ml][kc * 32 + q * 8];

    f32x4 y2[8];
    #pragma unroll
    for (int t = 0; t < 8; ++t) y2[t] = (f32x4){0.f, 0.f, 0.f, 0.f};

    for (int c4 = 0; c4 < 4; ++c4) {
        // GEMM2 chunk + gelu -> hs
        #pragma unroll
        for (int t2 = 0; t2 < 8; ++t2) {
            f32x4 hacc = {0.f, 0.f, 0.f, 0.f};
            const ushort_t* bp = fiwT + (size_t)(c4 * 128 + t2 * 16 + ml) * 128 + q * 8;
            #pragma unroll
            for (int kc = 0; kc < 4; ++kc)
                hacc = __builtin_amdgcn_mfma_f32_16x16x32_bf16(a2[kc], *(const bf16x8*)(bp + kc * 32), hacc, 0, 0, 0);
            float fb = fib[c4 * 128 + t2 * 16 + ml];
            #pragma unroll
            for (int r = 0; r < 4; ++r)
                hs[rloc + r][t2 * 16 + ml] = f2b(gelu_f(hacc[r] + fb));
        }
        __syncthreads();
        // GEMM3 chunk: y2 += h @ fow[c4*128..+128]
        bf16x8 a3[4];
        #pragma unroll
        for (int kc = 0; kc < 4; ++kc)
            a3[kc] = *(const bf16x8*)&hs[w * 16 + ml][kc * 32 + q * 8];
        #pragma unroll
        for (int t = 0; t < 8; ++t) {
            const ushort_t* bp = fowT + (size_t)(t * 16 + ml) * 512 + c4 * 128 + q * 8;
            #pragma unroll
            for (int kc = 0; kc < 4; ++kc)
                y2[t] = __builtin_amdgcn_mfma_f32_16x16x32_bf16(a3[kc], *(const bf16x8*)(bp + kc * 32), y2[t], 0, 0, 0);
        }
        __syncthreads();
    }

    // epilogue: out = x2 + y2 + fob
    #pragma unroll
    for (int t = 0; t < 8; ++t) {
        float ob = fob[t * 16 + ml];
        #pragma unroll
        for (int r = 0; r < 4; ++r) {
            int grow = g0 + rloc + r;
            if (grow < N_NODES)
                dout[(size_t)grow * 128 + t * 16 + ml] = x2[t][r] + y2[t][r] + ob;
        }
    }
}

extern "C" void kernel_launch(void* const* d_in, const int* in_sizes, int n_in,
                              void* d_out, int out_size, void* d_ws, size_t ws_size,
                              hipStream_t stream)
{
    const float* th    = (const float*)d_in[0];
    const int*   src   = (const int*)d_in[2];
    const int*   dst   = (const int*)d_in[3];
    const float* ebias = (const float*)d_in[4];
    const int*   inc   = (const int*)d_in[6];
    const float* ln1g  = (const float*)d_in[8];
    const float* ln1b  = (const float*)d_in[9];
    const float* qkvw  = (const float*)d_in[10];
    const float* qkvb  = (const float*)d_in[11];
    const float* riw   = (const float*)d_in[12];
    const float* rib   = (const float*)d_in[13];
    const float* rlg   = (const float*)d_in[14];
    const float* rlb   = (const float*)d_in[15];
    const float* fiw   = (const float*)d_in[16];
    const float* fib   = (const float*)d_in[17];
    const float* fow   = (const float*)d_in[18];
    const float* fob   = (const float*)d_in[19];

    char* ws = (char*)d_ws;
    ushort_t* qkvb16 = (ushort_t*)ws;                              ws += (size_t)N_NODES * 384 * 2;
    float*    scores = (float*)ws;                                 ws += (size_t)N_EDGES * 8 * 4;
    ushort_t* outw   = (ushort_t*)ws;                              ws += (size_t)N_NODES * 128 * 2;
    ushort_t* qkvwT  = (ushort_t*)ws;                              ws += (size_t)384 * 128 * 2;
    ushort_t* riwT   = (ushort_t*)ws;                              ws += (size_t)128 * 128 * 2;
    ushort_t* fiwT   = (ushort_t*)ws;                              ws += (size_t)512 * 128 * 2;
    ushort_t* fowT   = (ushort_t*)ws;                              ws += (size_t)128 * 512 * 2;
    float* dout = (float*)d_out;

    k_prep<<<768, 256, 0, stream>>>(qkvw, riw, fiw, fow, qkvwT, riwT, fiwT, fowT);
    k1_ln_qkv<<<(N_NODES + 63) / 64, 256, 0, stream>>>(th, ln1g, ln1b, qkvwT, qkvb, qkvb16);
    k2_edge_scores<<<(N_EDGES * 8) / 256, 256, 0, stream>>>(qkvb16, src, dst, ebias, scores);
    k3_agg<<<N_NODES, 128, 0, stream>>>(qkvb16, scores, inc, src, outw);
    k4_ffn<<<(N_NODES + 63) / 64, 256, 0, stream>>>(th, outw, riwT, rib, rlg, rlb,
                                                    fiwT, fib, fowT, fob, dout);
}

// Round 3
// 359.629 us; speedup vs baseline: 2.2021x; 1.2590x over previous
//
#include <hip/hip_runtime.h>
#include <math.h>

#define N_NODES 50000
#define N_EDGES 800000
#define QSCALE 0.08838834764831845f
#define LEPS 1e-5f

typedef unsigned short ushort_t;
typedef short bf16x8 __attribute__((ext_vector_type(8)));
typedef float f32x4 __attribute__((ext_vector_type(4)));

__device__ __forceinline__ ushort_t f2b(float f) {
    unsigned int u = __float_as_uint(f);
    u += 0x7FFF + ((u >> 16) & 1);   // RNE
    return (ushort_t)(u >> 16);
}
__device__ __forceinline__ float b2f(ushort_t v) {
    return __uint_as_float(((unsigned int)v) << 16);
}
__device__ __forceinline__ float gelu_f(float x) {
    const float c = 0.7978845608028654f; // sqrt(2/pi)
    float x3 = x * x * x;
    return 0.5f * x * (1.f + tanhf(c * (x + 0.044715f * x3)));
}
// async global->LDS DMA, 16B per lane (dest = wave-uniform base + lane*16)
__device__ __forceinline__ void gload16(const ushort_t* g, ushort_t* l) {
    __builtin_amdgcn_global_load_lds(
        (const __attribute__((address_space(1))) unsigned int*)g,
        (__attribute__((address_space(3))) unsigned int*)l, 16, 0, 0);
}

// ---- Prep: transpose+convert weights to bf16 W^T[n][k], 16B-chunk swizzled --
// within each 128-k row segment, chunk c (of 16B) stored at c ^ (n&7)
__global__ __launch_bounds__(256) void k_prep(
    const float* __restrict__ qkvw, const float* __restrict__ riw,
    const float* __restrict__ fiw,  const float* __restrict__ fow,
    ushort_t* __restrict__ qkvwT, ushort_t* __restrict__ riwT,
    ushort_t* __restrict__ fiwT,  ushort_t* __restrict__ fowT)
{
    int i = blockIdx.x * 256 + threadIdx.x;
    if (i < 384 * 128) {             // qkvw [128][384] -> qkvwT [384][128]
        int n = i % 384, k = i / 384;
        qkvwT[(size_t)n * 128 + (((k >> 3) ^ (n & 7)) << 3) + (k & 7)] = f2b(qkvw[k * 384 + n]);
        return;
    }
    i -= 384 * 128;
    if (i < 128 * 128) {             // riw [128][128] -> riwT [128][128]
        int n = i & 127, k = i >> 7;
        riwT[(size_t)n * 128 + (((k >> 3) ^ (n & 7)) << 3) + (k & 7)] = f2b(riw[k * 128 + n]);
        return;
    }
    i -= 128 * 128;
    if (i < 128 * 512) {             // fiw [128][512] -> fiwT [512][128]
        int n = i & 511, k = i >> 9;
        fiwT[(size_t)n * 128 + (((k >> 3) ^ (n & 7)) << 3) + (k & 7)] = f2b(fiw[k * 512 + n]);
        return;
    }
    i -= 128 * 512;
    if (i < 512 * 128) {             // fow [512][128] -> fowT [128][512], per-128 segs
        int n = i & 127, k = i >> 7;
        int seg = k >> 7, k7 = k & 127;
        fowT[(size_t)n * 512 + seg * 128 + (((k7 >> 3) ^ (n & 7)) << 3) + (k7 & 7)] = f2b(fow[k * 128 + n]);
    }
}

// ---- K1: LN(triplet_h) @ qkv_w + b -> qkv bf16 (q pre-scaled) ---------------
// 64 rows/block, 256 thr. Weights LDS-staged in 3 chunks of 128 cols.
__global__ __launch_bounds__(256) void k1_ln_qkv(
    const float* __restrict__ th, const float* __restrict__ g1, const float* __restrict__ b1,
    const ushort_t* __restrict__ wT, const float* __restrict__ bias, ushort_t* __restrict__ qkvb)
{
    __shared__ __align__(16) ushort_t xs[64][136];
    __shared__ __align__(16) ushort_t wbuf[16384];
    const int tid = threadIdx.x, lane = tid & 63, w = tid >> 6;
    const int g0 = blockIdx.x * 64;

    // stage chunk 0 weights (overlaps LN)
    #pragma unroll
    for (int t = 0; t < 8; ++t)
        gload16(wT + (size_t)(t * 256 + tid) * 8, wbuf + (t * 256 + tid) * 8);

    float ga = g1[lane], gb = g1[lane + 64];
    float ba = b1[lane], bb = b1[lane + 64];
    for (int rr = 0; rr < 16; ++rr) {
        int r = w * 16 + rr, grow = g0 + r;
        float x0 = 0.f, x1 = 0.f;
        if (grow < N_NODES) {
            x0 = th[(size_t)grow * 128 + lane];
            x1 = th[(size_t)grow * 128 + 64 + lane];
        }
        float s1 = x0 + x1, s2 = x0 * x0 + x1 * x1;
        #pragma unroll
        for (int off = 32; off; off >>= 1) { s1 += __shfl_xor(s1, off); s2 += __shfl_xor(s2, off); }
        float m = s1 * (1.f / 128.f);
        float v = s2 * (1.f / 128.f) - m * m;
        float rs = rsqrtf(v + LEPS);
        xs[r][lane]      = f2b((x0 - m) * rs * ga + ba);
        xs[r][lane + 64] = f2b((x1 - m) * rs * gb + bb);
    }
    __syncthreads();

    const int q = lane >> 4, ml = lane & 15;
    bf16x8 a[4];
    #pragma unroll
    for (int kc = 0; kc < 4; ++kc)
        a[kc] = *(const bf16x8*)&xs[w * 16 + ml][kc * 32 + q * 8];
    const int rbase = g0 + w * 16 + q * 4;

    for (int ch = 0; ch < 3; ++ch) {
        if (ch) {
            __syncthreads();   // previous chunk's ds_reads done
            #pragma unroll
            for (int t = 0; t < 8; ++t)
                gload16(wT + (size_t)ch * 16384 + (t * 256 + tid) * 8, wbuf + (t * 256 + tid) * 8);
            __syncthreads();
        } else {
            __syncthreads();   // (already synced once after LN; this pairs staging)
        }
        #pragma unroll
        for (int t2 = 0; t2 < 8; ++t2) {
            int n = t2 * 16 + ml;
            f32x4 acc = {0.f, 0.f, 0.f, 0.f};
            const ushort_t* bp = wbuf + n * 128;
            #pragma unroll
            for (int kc = 0; kc < 4; ++kc)
                acc = __builtin_amdgcn_mfma_f32_16x16x32_bf16(
                    a[kc], *(const bf16x8*)(bp + (((kc * 4 + q) ^ (ml & 7)) << 3)), acc, 0, 0, 0);
            int col = ch * 128 + n;
            float bs = bias[col];
            float sc = (ch == 0) ? QSCALE : 1.f;
            #pragma unroll
            for (int r = 0; r < 4; ++r) {
                int grow = rbase + r;
                if (grow < N_NODES)
                    qkvb[(size_t)grow * 384 + col] = f2b((acc[r] + bs) * sc);
            }
        }
    }
}

// ---- K2: per-edge scores = dot(q[src],k[dst]) + edge_bias -------------------
__global__ __launch_bounds__(256) void k2_edge_scores(
    const ushort_t* __restrict__ qkvb, const int* __restrict__ src, const int* __restrict__ dst,
    const float* __restrict__ eb, float* __restrict__ scores)
{
    int t = blockIdx.x * 256 + threadIdx.x;
    int e = t >> 3, h = t & 7;
    if (e >= N_EDGES) return;
    int s = src[e], d = dst[e];
    const uint4* qp = (const uint4*)(qkvb + (size_t)s * 384 + h * 16);
    const uint4* kp = (const uint4*)(qkvb + (size_t)d * 384 + 128 + h * 16);
    float acc = 0.f;
    #pragma unroll
    for (int i = 0; i < 2; ++i) {
        uint4 qa = qp[i], ka = kp[i];
        const unsigned int* qu = (const unsigned int*)&qa;
        const unsigned int* ku = (const unsigned int*)&ka;
        #pragma unroll
        for (int j = 0; j < 4; ++j) {
            float q0 = __uint_as_float(qu[j] << 16);
            float q1 = __uint_as_float(qu[j] & 0xffff0000u);
            float k0 = __uint_as_float(ku[j] << 16);
            float k1 = __uint_as_float(ku[j] & 0xffff0000u);
            acc = fmaf(q0, k0, acc);
            acc = fmaf(q1, k1, acc);
        }
    }
    scores[t] = acc + eb[t];
}

// ---- K3: per-node softmax over K=16 incoming, aggregate v -------------------
__global__ __launch_bounds__(128) void k3_agg(
    const ushort_t* __restrict__ qkvb, const float* __restrict__ scores,
    const int* __restrict__ inc_idx, const int* __restrict__ src,
    ushort_t* __restrict__ outw)
{
    __shared__ int es[16];
    __shared__ int ss[16];
    __shared__ float sc[16][8];
    int n = blockIdx.x;
    int j = threadIdx.x;   // 0..127 = h*16+dh
    int h = j >> 4;
    if (j < 16) {
        int e = inc_idx[(size_t)n * 16 + j];
        if (e < 0) e = 0;
        es[j] = e;
        ss[j] = src[e];
    }
    __syncthreads();
    {
        int k = j >> 3, hh = j & 7;
        sc[k][hh] = scores[(size_t)es[k] * 8 + hh];
    }
    __syncthreads();
    float m = -1e30f;
    #pragma unroll
    for (int k = 0; k < 16; k++) m = fmaxf(m, sc[k][h]);
    float p[16];
    float sum = 0.f;
    #pragma unroll
    for (int k = 0; k < 16; k++) { p[k] = __expf(sc[k][h] - m); sum += p[k]; }
    float inv = 1.f / sum;
    float acc = 0.f;
    #pragma unroll
    for (int k = 0; k < 16; k++) acc += p[k] * b2f(qkvb[(size_t)ss[k] * 384 + 256 + j]);
    outw[(size_t)n * 128 + j] = f2b(acc * inv);
}

// ---- K4: x2 = th + out@riw + rib; LN; FFN(gelu); out = x2 + y ---------------
// 64 rows/block, 256 thr. All B-matrices LDS-staged (32KB chunks, swizzled).
__global__ __launch_bounds__(256) void k4_ffn(
    const float* __restrict__ th, const ushort_t* __restrict__ outw,
    const ushort_t* __restrict__ riwT, const float* __restrict__ rib,
    const float* __restrict__ rlg, const float* __restrict__ rlb,
    const ushort_t* __restrict__ fiwT, const float* __restrict__ fib,
    const ushort_t* __restrict__ fowT, const float* __restrict__ fob,
    float* __restrict__ dout)
{
    __shared__ __align__(16) ushort_t ys[64][136];
    __shared__ __align__(16) ushort_t hs[64][136];
    __shared__ __align__(16) ushort_t wbuf[16384];
    const int tid = threadIdx.x, lane = tid & 63, w = tid >> 6;
    const int g0 = blockIdx.x * 64;
    const int q = lane >> 4, ml = lane & 15;
    const int rloc = w * 16 + q * 4;

    // stage riw weights (DMA overlaps A-fragment loads)
    #pragma unroll
    for (int t = 0; t < 8; ++t)
        gload16(riwT + (size_t)(t * 256 + tid) * 8, wbuf + (t * 256 + tid) * 8);

    // GEMM1 A-fragments straight from global (bf16 outw, L2/L3-resident)
    int arow = g0 + w * 16 + ml; if (arow > N_NODES - 1) arow = N_NODES - 1;
    bf16x8 a[4];
    #pragma unroll
    for (int kc = 0; kc < 4; ++kc)
        a[kc] = *(const bf16x8*)(outw + (size_t)arow * 128 + kc * 32 + q * 8);
    __syncthreads();

    // GEMM1: x2 = out @ riw
    f32x4 x2[8];
    #pragma unroll
    for (int t = 0; t < 8; ++t) {
        f32x4 acc = {0.f, 0.f, 0.f, 0.f};
        const ushort_t* bp = wbuf + (t * 16 + ml) * 128;
        #pragma unroll
        for (int kc = 0; kc < 4; ++kc)
            acc = __builtin_amdgcn_mfma_f32_16x16x32_bf16(
                a[kc], *(const bf16x8*)(bp + (((kc * 4 + q) ^ (ml & 7)) << 3)), acc, 0, 0, 0);
        x2[t] = acc;
    }
    #pragma unroll
    for (int t = 0; t < 8; ++t) {
        float bb = rib[t * 16 + ml];
        #pragma unroll
        for (int r = 0; r < 4; ++r) {
            int grow = g0 + rloc + r;
            float tv = (grow < N_NODES) ? th[(size_t)grow * 128 + t * 16 + ml] : 0.f;
            x2[t][r] += bb + tv;
        }
    }

    // LN(x2) -> ys (bf16); row spread over 16 ml-lanes (8 cols each)
    {
        float rg[8], rbv[8];
        #pragma unroll
        for (int t = 0; t < 8; ++t) { rg[t] = rlg[t * 16 + ml]; rbv[t] = rlb[t * 16 + ml]; }
        #pragma unroll
        for (int r = 0; r < 4; ++r) {
            float s1 = 0.f, s2 = 0.f;
            #pragma unroll
            for (int t = 0; t < 8; ++t) { float v = x2[t][r]; s1 += v; s2 += v * v; }
            #pragma unroll
            for (int off = 1; off < 16; off <<= 1) { s1 += __shfl_xor(s1, off); s2 += __shfl_xor(s2, off); }
            float m = s1 * (1.f / 128.f);
            float v = s2 * (1.f / 128.f) - m * m;
            float rs = rsqrtf(v + LEPS);
            #pragma unroll
            for (int t = 0; t < 8; ++t)
                ys[rloc + r][t * 16 + ml] = f2b((x2[t][r] - m) * rs * rg[t] + rbv[t]);
        }
    }
    __syncthreads();   // ys ready; GEMM1 wbuf reads done

    bf16x8 a2[4];
    #pragma unroll
    for (int kc = 0; kc < 4; ++kc)
        a2[kc] = *(const bf16x8*)&ys[w * 16 + ml][kc * 32 + q * 8];

    f32x4 y2[8];
    #pragma unroll
    for (int t = 0; t < 8; ++t) y2[t] = (f32x4){0.f, 0.f, 0.f, 0.f};

    for (int c4 = 0; c4 < 4; ++c4) {
        // stage fiw chunk
        #pragma unroll
        for (int t = 0; t < 8; ++t)
            gload16(fiwT + (size_t)c4 * 16384 + (t * 256 + tid) * 8, wbuf + (t * 256 + tid) * 8);
        __syncthreads();
        // GEMM2 chunk + gelu -> hs
        #pragma unroll
        for (int t2 = 0; t2 < 8; ++t2) {
            f32x4 hacc = {0.f, 0.f, 0.f, 0.f};
            const ushort_t* bp = wbuf + (t2 * 16 + ml) * 128;
            #pragma unroll
            for (int kc = 0; kc < 4; ++kc)
                hacc = __builtin_amdgcn_mfma_f32_16x16x32_bf16(
                    a2[kc], *(const bf16x8*)(bp + (((kc * 4 + q) ^ (ml & 7)) << 3)), hacc, 0, 0, 0);
            float fb = fib[c4 * 128 + t2 * 16 + ml];
            #pragma unroll
            for (int r = 0; r < 4; ++r)
                hs[rloc + r][t2 * 16 + ml] = f2b(gelu_f(hacc[r] + fb));
        }
        __syncthreads();   // hs ready + GEMM2 wbuf reads done
        // stage fow chunk: rows n=0..127, k-segment c4 (pre-swizzled in prep)
        #pragma unroll
        for (int t = 0; t < 8; ++t) {
            int idx = t * 256 + tid;
            int n = idx >> 4, c = idx & 15;
            gload16(fowT + (size_t)n * 512 + c4 * 128 + c * 8, wbuf + idx * 8);
        }
        __syncthreads();
        // GEMM3 chunk: y2 += h @ fow_seg
        bf16x8 a3[4];
        #pragma unroll
        for (int kc = 0; kc < 4; ++kc)
            a3[kc] = *(const bf16x8*)&hs[w * 16 + ml][kc * 32 + q * 8];
        #pragma unroll
        for (int t = 0; t < 8; ++t) {
            const ushort_t* bp = wbuf + (t * 16 + ml) * 128;
            #pragma unroll
            for (int kc = 0; kc < 4; ++kc)
                y2[t] = __builtin_amdgcn_mfma_f32_16x16x32_bf16(
                    a3[kc], *(const bf16x8*)(bp + (((kc * 4 + q) ^ (ml & 7)) << 3)), y2[t], 0, 0, 0);
        }
        __syncthreads();   // wbuf + hs free for next c4
    }

    // epilogue: out = x2 + y2 + fob
    #pragma unroll
    for (int t = 0; t < 8; ++t) {
        float ob = fob[t * 16 + ml];
        #pragma unroll
        for (int r = 0; r < 4; ++r) {
            int grow = g0 + rloc + r;
            if (grow < N_NODES)
                dout[(size_t)grow * 128 + t * 16 + ml] = x2[t][r] + y2[t][r] + ob;
        }
    }
}

extern "C" void kernel_launch(void* const* d_in, const int* in_sizes, int n_in,
                              void* d_out, int out_size, void* d_ws, size_t ws_size,
                              hipStream_t stream)
{
    const float* th    = (const float*)d_in[0];
    const int*   src   = (const int*)d_in[2];
    const int*   dst   = (const int*)d_in[3];
    const float* ebias = (const float*)d_in[4];
    const int*   inc   = (const int*)d_in[6];
    const float* ln1g  = (const float*)d_in[8];
    const float* ln1b  = (const float*)d_in[9];
    const float* qkvw  = (const float*)d_in[10];
    const float* qkvb  = (const float*)d_in[11];
    const float* riw   = (const float*)d_in[12];
    const float* rib   = (const float*)d_in[13];
    const float* rlg   = (const float*)d_in[14];
    const float* rlb   = (const float*)d_in[15];
    const float* fiw   = (const float*)d_in[16];
    const float* fib   = (const float*)d_in[17];
    const float* fow   = (const float*)d_in[18];
    const float* fob   = (const float*)d_in[19];

    char* ws = (char*)d_ws;
    ushort_t* qkvb16 = (ushort_t*)ws;                              ws += (size_t)N_NODES * 384 * 2;
    float*    scores = (float*)ws;                                 ws += (size_t)N_EDGES * 8 * 4;
    ushort_t* outw   = (ushort_t*)ws;                              ws += (size_t)N_NODES * 128 * 2;
    ushort_t* qkvwT  = (ushort_t*)ws;                              ws += (size_t)384 * 128 * 2;
    ushort_t* riwT   = (ushort_t*)ws;                              ws += (size_t)128 * 128 * 2;
    ushort_t* fiwT   = (ushort_t*)ws;                              ws += (size_t)512 * 128 * 2;
    ushort_t* fowT   = (ushort_t*)ws;                              ws += (size_t)128 * 512 * 2;
    float* dout = (float*)d_out;

    k_prep<<<768, 256, 0, stream>>>(qkvw, riw, fiw, fow, qkvwT, riwT, fiwT, fowT);
    k1_ln_qkv<<<(N_NODES + 63) / 64, 256, 0, stream>>>(th, ln1g, ln1b, qkvwT, qkvb, qkvb16);
    k2_edge_scores<<<(N_EDGES * 8) / 256, 256, 0, stream>>>(qkvb16, src, dst, ebias, scores);
    k3_agg<<<N_NODES, 128, 0, stream>>>(qkvb16, scores, inc, src, outw);
    k4_ffn<<<(N_NODES + 63) / 64, 256, 0, stream>>>(th, outw, riwT, rib, rlg, rlb,
                                                    fiwT, fib, fowT, fob, dout);
}

// Round 4
// 318.947 us; speedup vs baseline: 2.4830x; 1.1276x over previous
//
#include <hip/hip_runtime.h>
#include <math.h>

#define N_NODES 50000
#define N_EDGES 800000
#define QSCALE 0.08838834764831845f
#define LEPS 1e-5f

typedef unsigned short ushort_t;
typedef unsigned char uchar_t;
typedef short bf16x8 __attribute__((ext_vector_type(8)));
typedef float f32x4 __attribute__((ext_vector_type(4)));
typedef float f32x2 __attribute__((ext_vector_type(2)));

__device__ __forceinline__ ushort_t f2b(float f) {
    unsigned int u = __float_as_uint(f);
    u += 0x7FFF + ((u >> 16) & 1);   // RNE
    return (ushort_t)(u >> 16);
}
__device__ __forceinline__ uchar_t f2fp8(float f) {
    unsigned int pk = __builtin_amdgcn_cvt_pk_fp8_f32(f, f, 0, false);
    return (uchar_t)(pk & 0xff);
}
__device__ __forceinline__ float gelu_f(float x) {
    const float c = 0.7978845608028654f; // sqrt(2/pi)
    float x3 = x * x * x;
    return 0.5f * x * (1.f + tanhf(c * (x + 0.044715f * x3)));
}
// async global->LDS DMA, 16B per lane (dest = wave-uniform base + lane*16)
__device__ __forceinline__ void gload16(const ushort_t* g, ushort_t* l) {
    __builtin_amdgcn_global_load_lds(
        (const __attribute__((address_space(1))) unsigned int*)g,
        (__attribute__((address_space(3))) unsigned int*)l, 16, 0, 0);
}

// ---- Prep: transpose+convert weights to bf16 W^T[n][k], 16B-chunk swizzled --
__global__ __launch_bounds__(256) void k_prep(
    const float* __restrict__ qkvw, const float* __restrict__ riw,
    const float* __restrict__ fiw,  const float* __restrict__ fow,
    ushort_t* __restrict__ qkvwT, ushort_t* __restrict__ riwT,
    ushort_t* __restrict__ fiwT,  ushort_t* __restrict__ fowT)
{
    int i = blockIdx.x * 256 + threadIdx.x;
    if (i < 384 * 128) {             // qkvw [128][384] -> qkvwT [384][128]
        int n = i % 384, k = i / 384;
        qkvwT[(size_t)n * 128 + (((k >> 3) ^ (n & 7)) << 3) + (k & 7)] = f2b(qkvw[k * 384 + n]);
        return;
    }
    i -= 384 * 128;
    if (i < 128 * 128) {             // riw [128][128] -> riwT [128][128]
        int n = i & 127, k = i >> 7;
        riwT[(size_t)n * 128 + (((k >> 3) ^ (n & 7)) << 3) + (k & 7)] = f2b(riw[k * 128 + n]);
        return;
    }
    i -= 128 * 128;
    if (i < 128 * 512) {             // fiw [128][512] -> fiwT [512][128]
        int n = i & 511, k = i >> 9;
        fiwT[(size_t)n * 128 + (((k >> 3) ^ (n & 7)) << 3) + (k & 7)] = f2b(fiw[k * 512 + n]);
        return;
    }
    i -= 128 * 512;
    if (i < 512 * 128) {             // fow [512][128] -> fowT [128][512], per-128 segs
        int n = i & 127, k = i >> 7;
        int seg = k >> 7, k7 = k & 127;
        fowT[(size_t)n * 512 + seg * 128 + (((k7 >> 3) ^ (n & 7)) << 3) + (k7 & 7)] = f2b(fow[k * 128 + n]);
    }
}

// ---- K1: LN(triplet_h) @ qkv_w + b -> q8/k8/v8 (fp8 e4m3, q UNscaled) -------
__global__ __launch_bounds__(256) void k1_ln_qkv(
    const float* __restrict__ th, const float* __restrict__ g1, const float* __restrict__ b1,
    const ushort_t* __restrict__ wT, const float* __restrict__ bias,
    uchar_t* __restrict__ q8, uchar_t* __restrict__ k8, uchar_t* __restrict__ v8)
{
    __shared__ __align__(16) ushort_t xs[64][136];
    __shared__ __align__(16) ushort_t wbuf[16384];
    const int tid = threadIdx.x, lane = tid & 63, w = tid >> 6;
    const int g0 = blockIdx.x * 64;

    // stage chunk 0 weights (overlaps LN)
    #pragma unroll
    for (int t = 0; t < 8; ++t)
        gload16(wT + (size_t)(t * 256 + tid) * 8, wbuf + (t * 256 + tid) * 8);

    float ga = g1[lane], gb = g1[lane + 64];
    float ba = b1[lane], bb = b1[lane + 64];
    for (int rr = 0; rr < 16; ++rr) {
        int r = w * 16 + rr, grow = g0 + r;
        float x0 = 0.f, x1 = 0.f;
        if (grow < N_NODES) {
            x0 = th[(size_t)grow * 128 + lane];
            x1 = th[(size_t)grow * 128 + 64 + lane];
        }
        float s1 = x0 + x1, s2 = x0 * x0 + x1 * x1;
        #pragma unroll
        for (int off = 32; off; off >>= 1) { s1 += __shfl_xor(s1, off); s2 += __shfl_xor(s2, off); }
        float m = s1 * (1.f / 128.f);
        float v = s2 * (1.f / 128.f) - m * m;
        float rs = rsqrtf(v + LEPS);
        xs[r][lane]      = f2b((x0 - m) * rs * ga + ba);
        xs[r][lane + 64] = f2b((x1 - m) * rs * gb + bb);
    }
    __syncthreads();

    const int q = lane >> 4, ml = lane & 15;
    bf16x8 a[4];
    #pragma unroll
    for (int kc = 0; kc < 4; ++kc)
        a[kc] = *(const bf16x8*)&xs[w * 16 + ml][kc * 32 + q * 8];
    const int rbase = g0 + w * 16 + q * 4;

    for (int ch = 0; ch < 3; ++ch) {
        if (ch) {
            __syncthreads();
            #pragma unroll
            for (int t = 0; t < 8; ++t)
                gload16(wT + (size_t)ch * 16384 + (t * 256 + tid) * 8, wbuf + (t * 256 + tid) * 8);
            __syncthreads();
        } else {
            __syncthreads();
        }
        uchar_t* outp = (ch == 0) ? q8 : (ch == 1) ? k8 : v8;
        #pragma unroll
        for (int t2 = 0; t2 < 8; ++t2) {
            int n = t2 * 16 + ml;
            f32x4 acc = {0.f, 0.f, 0.f, 0.f};
            const ushort_t* bp = wbuf + n * 128;
            #pragma unroll
            for (int kc = 0; kc < 4; ++kc)
                acc = __builtin_amdgcn_mfma_f32_16x16x32_bf16(
                    a[kc], *(const bf16x8*)(bp + (((kc * 4 + q) ^ (ml & 7)) << 3)), acc, 0, 0, 0);
            float bs = bias[ch * 128 + n];
            #pragma unroll
            for (int r = 0; r < 4; ++r) {
                int grow = rbase + r;
                if (grow < N_NODES)
                    outp[(size_t)grow * 128 + n] = f2fp8(acc[r] + bs);
            }
        }
    }
}

// ---- K2: per-edge scores = QSCALE*dot(q[src],k[dst]) + edge_bias ------------
__global__ __launch_bounds__(256) void k2_edge_scores(
    const uchar_t* __restrict__ q8, const uchar_t* __restrict__ k8,
    const int* __restrict__ src, const int* __restrict__ dst,
    const float* __restrict__ eb, float* __restrict__ scores)
{
    int t = blockIdx.x * 256 + threadIdx.x;
    int e = t >> 3, h = t & 7;
    if (e >= N_EDGES) return;
    int s = src[e], d = dst[e];
    uint4 qa = *(const uint4*)(q8 + (size_t)s * 128 + h * 16);
    uint4 ka = *(const uint4*)(k8 + (size_t)d * 128 + h * 16);
    const unsigned int* qu = (const unsigned int*)&qa;
    const unsigned int* ku = (const unsigned int*)&ka;
    float acc = 0.f;
    #pragma unroll
    for (int j = 0; j < 4; ++j) {
        f32x2 q0 = __builtin_amdgcn_cvt_pk_f32_fp8(qu[j], false);
        f32x2 q1 = __builtin_amdgcn_cvt_pk_f32_fp8(qu[j], true);
        f32x2 k0 = __builtin_amdgcn_cvt_pk_f32_fp8(ku[j], false);
        f32x2 k1 = __builtin_amdgcn_cvt_pk_f32_fp8(ku[j], true);
        acc = fmaf(q0.x, k0.x, acc); acc = fmaf(q0.y, k0.y, acc);
        acc = fmaf(q1.x, k1.x, acc); acc = fmaf(q1.y, k1.y, acc);
    }
    scores[t] = acc * QSCALE + eb[t];
}

// ---- K3: per-node softmax over K=16 incoming, aggregate v (2 nodes/block) ---
__global__ __launch_bounds__(256) void k3_agg(
    const uchar_t* __restrict__ v8, const float* __restrict__ scores,
    const int* __restrict__ inc_idx, const int* __restrict__ src,
    ushort_t* __restrict__ outw)
{
    __shared__ int es[2][16];
    __shared__ int ss[2][16];
    __shared__ float sc[2][16][8];
    int loc = threadIdx.x >> 7;
    int j = threadIdx.x & 127;   // 0..127 = h*16+dh
    int n = blockIdx.x * 2 + loc;   // N_NODES even -> always valid
    int h = j >> 4;
    if (j < 16) {
        int e = inc_idx[(size_t)n * 16 + j];
        if (e < 0) e = 0;
        es[loc][j] = e;
        ss[loc][j] = src[e];
    }
    __syncthreads();
    {
        int k = j >> 3, hh = j & 7;
        sc[loc][k][hh] = scores[(size_t)es[loc][k] * 8 + hh];
    }
    __syncthreads();
    float m = -1e30f;
    #pragma unroll
    for (int k = 0; k < 16; k++) m = fmaxf(m, sc[loc][k][h]);
    float p[16];
    float sum = 0.f;
    #pragma unroll
    for (int k = 0; k < 16; k++) { p[k] = __expf(sc[loc][k][h] - m); sum += p[k]; }
    float inv = 1.f / sum;
    float acc = 0.f;
    #pragma unroll
    for (int k = 0; k < 16; k++)
        acc += p[k] * __builtin_amdgcn_cvt_f32_fp8((int)v8[(size_t)ss[loc][k] * 128 + j], 0);
    outw[(size_t)n * 128 + j] = f2b(acc * inv);
}

// ---- K4: x2 = th + out@riw + rib; LN; FFN(gelu); out = x2 + y ---------------
// ys/hs use XOR column-group swizzle: logical group g of row n stored at g^((n>>2)&3)
__global__ __launch_bounds__(256) void k4_ffn(
    const float* __restrict__ th, const ushort_t* __restrict__ outw,
    const ushort_t* __restrict__ riwT, const float* __restrict__ rib,
    const float* __restrict__ rlg, const float* __restrict__ rlb,
    const ushort_t* __restrict__ fiwT, const float* __restrict__ fib,
    const ushort_t* __restrict__ fowT, const float* __restrict__ fob,
    float* __restrict__ dout)
{
    __shared__ __align__(16) ushort_t ys[64][136];
    __shared__ __align__(16) ushort_t hs[64][136];
    __shared__ __align__(16) ushort_t wbuf[16384];
    const int tid = threadIdx.x, lane = tid & 63, w = tid >> 6;
    const int g0 = blockIdx.x * 64;
    const int q = lane >> 4, ml = lane & 15;
    const int rloc = w * 16 + q * 4;
    const int aswz = (ml >> 2) & 3;      // read-side row swizzle for rows w*16+ml

    // stage riw weights (DMA overlaps A-fragment loads)
    #pragma unroll
    for (int t = 0; t < 8; ++t)
        gload16(riwT + (size_t)(t * 256 + tid) * 8, wbuf + (t * 256 + tid) * 8);

    // GEMM1 A-fragments straight from global (bf16 outw, L2/L3-resident)
    int arow = g0 + w * 16 + ml; if (arow > N_NODES - 1) arow = N_NODES - 1;
    bf16x8 a[4];
    #pragma unroll
    for (int kc = 0; kc < 4; ++kc)
        a[kc] = *(const bf16x8*)(outw + (size_t)arow * 128 + kc * 32 + q * 8);
    __syncthreads();

    // GEMM1: x2 = out @ riw
    f32x4 x2[8];
    #pragma unroll
    for (int t = 0; t < 8; ++t) {
        f32x4 acc = {0.f, 0.f, 0.f, 0.f};
        const ushort_t* bp = wbuf + (t * 16 + ml) * 128;
        #pragma unroll
        for (int kc = 0; kc < 4; ++kc)
            acc = __builtin_amdgcn_mfma_f32_16x16x32_bf16(
                a[kc], *(const bf16x8*)(bp + (((kc * 4 + q) ^ (ml & 7)) << 3)), acc, 0, 0, 0);
        x2[t] = acc;
    }
    #pragma unroll
    for (int t = 0; t < 8; ++t) {
        float bb = rib[t * 16 + ml];
        #pragma unroll
        for (int r = 0; r < 4; ++r) {
            int grow = g0 + rloc + r;
            float tv = (grow < N_NODES) ? th[(size_t)grow * 128 + t * 16 + ml] : 0.f;
            x2[t][r] += bb + tv;
        }
    }

    // LN(x2) -> ys (bf16, swizzled); row spread over 16 ml-lanes (8 cols each)
    {
        float rg[8], rbv[8];
        #pragma unroll
        for (int t = 0; t < 8; ++t) { rg[t] = rlg[t * 16 + ml]; rbv[t] = rlb[t * 16 + ml]; }
        #pragma unroll
        for (int r = 0; r < 4; ++r) {
            float s1 = 0.f, s2 = 0.f;
            #pragma unroll
            for (int t = 0; t < 8; ++t) { float v = x2[t][r]; s1 += v; s2 += v * v; }
            #pragma unroll
            for (int off = 1; off < 16; off <<= 1) { s1 += __shfl_xor(s1, off); s2 += __shfl_xor(s2, off); }
            float m = s1 * (1.f / 128.f);
            float v = s2 * (1.f / 128.f) - m * m;
            float rs = rsqrtf(v + LEPS);
            #pragma unroll
            for (int t = 0; t < 8; ++t) {
                int G = (2 * t + (ml >> 3)) ^ q;   // (n>>2)&3 == q for rows rloc+r
                ys[rloc + r][G * 8 + (ml & 7)] = f2b((x2[t][r] - m) * rs * rg[t] + rbv[t]);
            }
        }
    }
    __syncthreads();   // ys ready; GEMM1 wbuf reads done

    bf16x8 a2[4];
    #pragma unroll
    for (int kc = 0; kc < 4; ++kc)
        a2[kc] = *(const bf16x8*)&ys[w * 16 + ml][(((kc * 4 + q) ^ aswz) << 3)];

    f32x4 y2[8];
    #pragma unroll
    for (int t = 0; t < 8; ++t) y2[t] = (f32x4){0.f, 0.f, 0.f, 0.f};

    for (int c4 = 0; c4 < 4; ++c4) {
        // stage fiw chunk
        #pragma unroll
        for (int t = 0; t < 8; ++t)
            gload16(fiwT + (size_t)c4 * 16384 + (t * 256 + tid) * 8, wbuf + (t * 256 + tid) * 8);
        __syncthreads();
        // GEMM2 chunk + gelu -> hs (swizzled)
        #pragma unroll
        for (int t2 = 0; t2 < 8; ++t2) {
            f32x4 hacc = {0.f, 0.f, 0.f, 0.f};
            const ushort_t* bp = wbuf + (t2 * 16 + ml) * 128;
            #pragma unroll
            for (int kc = 0; kc < 4; ++kc)
                hacc = __builtin_amdgcn_mfma_f32_16x16x32_bf16(
                    a2[kc], *(const bf16x8*)(bp + (((kc * 4 + q) ^ (ml & 7)) << 3)), hacc, 0, 0, 0);
            float fb = fib[c4 * 128 + t2 * 16 + ml];
            int G = (2 * t2 + (ml >> 3)) ^ q;
            #pragma unroll
            for (int r = 0; r < 4; ++r)
                hs[rloc + r][G * 8 + (ml & 7)] = f2b(gelu_f(hacc[r] + fb));
        }
        __syncthreads();   // hs ready + GEMM2 wbuf reads done
        // stage fow chunk: rows n=0..127, k-segment c4 (pre-swizzled in prep)
        #pragma unroll
        for (int t = 0; t < 8; ++t) {
            int idx = t * 256 + tid;
            int n = idx >> 4, c = idx & 15;
            gload16(fowT + (size_t)n * 512 + c4 * 128 + c * 8, wbuf + idx * 8);
        }
        __syncthreads();
        // GEMM3 chunk: y2 += h @ fow_seg
        bf16x8 a3[4];
        #pragma unroll
        for (int kc = 0; kc < 4; ++kc)
            a3[kc] = *(const bf16x8*)&hs[w * 16 + ml][(((kc * 4 + q) ^ aswz) << 3)];
        #pragma unroll
        for (int t = 0; t < 8; ++t) {
            const ushort_t* bp = wbuf + (t * 16 + ml) * 128;
            #pragma unroll
            for (int kc = 0; kc < 4; ++kc)
                y2[t] = __builtin_amdgcn_mfma_f32_16x16x32_bf16(
                    a3[kc], *(const bf16x8*)(bp + (((kc * 4 + q) ^ (ml & 7)) << 3)), y2[t], 0, 0, 0);
        }
        __syncthreads();   // wbuf + hs free for next c4
    }

    // epilogue: out = x2 + y2 + fob
    #pragma unroll
    for (int t = 0; t < 8; ++t) {
        float ob = fob[t * 16 + ml];
        #pragma unroll
        for (int r = 0; r < 4; ++r) {
            int grow = g0 + rloc + r;
            if (grow < N_NODES)
                dout[(size_t)grow * 128 + t * 16 + ml] = x2[t][r] + y2[t][r] + ob;
        }
    }
}

extern "C" void kernel_launch(void* const* d_in, const int* in_sizes, int n_in,
                              void* d_out, int out_size, void* d_ws, size_t ws_size,
                              hipStream_t stream)
{
    const float* th    = (const float*)d_in[0];
    const int*   src   = (const int*)d_in[2];
    const int*   dst   = (const int*)d_in[3];
    const float* ebias = (const float*)d_in[4];
    const int*   inc   = (const int*)d_in[6];
    const float* ln1g  = (const float*)d_in[8];
    const float* ln1b  = (const float*)d_in[9];
    const float* qkvw  = (const float*)d_in[10];
    const float* qkvb  = (const float*)d_in[11];
    const float* riw   = (const float*)d_in[12];
    const float* rib   = (const float*)d_in[13];
    const float* rlg   = (const float*)d_in[14];
    const float* rlb   = (const float*)d_in[15];
    const float* fiw   = (const float*)d_in[16];
    const float* fib   = (const float*)d_in[17];
    const float* fow   = (const float*)d_in[18];
    const float* fob   = (const float*)d_in[19];

    char* ws = (char*)d_ws;
    uchar_t* q8      = (uchar_t*)ws;                               ws += (size_t)N_NODES * 128;
    uchar_t* k8      = (uchar_t*)ws;                               ws += (size_t)N_NODES * 128;
    uchar_t* v8      = (uchar_t*)ws;                               ws += (size_t)N_NODES * 128;
    float*    scores = (float*)ws;                                 ws += (size_t)N_EDGES * 8 * 4;
    ushort_t* outw   = (ushort_t*)ws;                              ws += (size_t)N_NODES * 128 * 2;
    ushort_t* qkvwT  = (ushort_t*)ws;                              ws += (size_t)384 * 128 * 2;
    ushort_t* riwT   = (ushort_t*)ws;                              ws += (size_t)128 * 128 * 2;
    ushort_t* fiwT   = (ushort_t*)ws;                              ws += (size_t)512 * 128 * 2;
    ushort_t* fowT   = (ushort_t*)ws;                              ws += (size_t)128 * 512 * 2;
    float* dout = (float*)d_out;

    k_prep<<<768, 256, 0, stream>>>(qkvw, riw, fiw, fow, qkvwT, riwT, fiwT, fowT);
    k1_ln_qkv<<<(N_NODES + 63) / 64, 256, 0, stream>>>(th, ln1g, ln1b, qkvwT, qkvb, q8, k8, v8);
    k2_edge_scores<<<(N_EDGES * 8) / 256, 256, 0, stream>>>(q8, k8, src, dst, ebias, scores);
    k3_agg<<<N_NODES / 2, 256, 0, stream>>>(v8, scores, inc, src, outw);
    k4_ffn<<<(N_NODES + 63) / 64, 256, 0, stream>>>(th, outw, riwT, rib, rlg, rlb,
                                                    fiwT, fib, fowT, fob, dout);
}

// Round 5
// 315.104 us; speedup vs baseline: 2.5132x; 1.0122x over previous
//
#include <hip/hip_runtime.h>
#include <math.h>

#define N_NODES 50000
#define N_EDGES 800000
#define QSCALE 0.08838834764831845f
#define LEPS 1e-5f

typedef unsigned short ushort_t;
typedef unsigned char uchar_t;
typedef short bf16x8 __attribute__((ext_vector_type(8)));
typedef float f32x4 __attribute__((ext_vector_type(4)));
typedef float f32x2 __attribute__((ext_vector_type(2)));

__device__ __forceinline__ ushort_t f2b(float f) {
    unsigned int u = __float_as_uint(f);
    u += 0x7FFF + ((u >> 16) & 1);   // RNE
    return (ushort_t)(u >> 16);
}
__device__ __forceinline__ uchar_t f2fp8(float f) {
    unsigned int pk = __builtin_amdgcn_cvt_pk_fp8_f32(f, f, 0, false);
    return (uchar_t)(pk & 0xff);
}
__device__ __forceinline__ float gelu_f(float x) {
    const float c = 0.7978845608028654f; // sqrt(2/pi)
    float x3 = x * x * x;
    return 0.5f * x * (1.f + tanhf(c * (x + 0.044715f * x3)));
}
// async global->LDS DMA, 16B per lane (dest = wave-uniform base + lane*16)
__device__ __forceinline__ void gload16(const ushort_t* g, ushort_t* l) {
    __builtin_amdgcn_global_load_lds(
        (const __attribute__((address_space(1))) unsigned int*)g,
        (__attribute__((address_space(3))) unsigned int*)l, 16, 0, 0);
}
// fragment-order index inside a 128x128 bf16 block:
// tile (t2=n>>4, kc=k>>5) of 1KB; within: lane(q=(k>>3)&3, ml=n&15)*16B + (k&7)*2B
__device__ __forceinline__ int frag_idx(int n7, int k7) {
    return ((n7 >> 4) * 4 + (k7 >> 5)) * 512 + ((k7 >> 3) & 3) * 128 + (n7 & 15) * 8 + (k7 & 7);
}

// ---- Prep: weights -> bf16 fragment-order wave tiles ------------------------
__global__ __launch_bounds__(256) void k_prep(
    const float* __restrict__ qkvw, const float* __restrict__ riw,
    const float* __restrict__ fiw,  const float* __restrict__ fow,
    ushort_t* __restrict__ qkvwT, ushort_t* __restrict__ riwT,
    ushort_t* __restrict__ fiwT,  ushort_t* __restrict__ fowT)
{
    int i = blockIdx.x * 256 + threadIdx.x;
    if (i < 384 * 128) {             // qkvw [128 k][384 n]
        int n = i >> 7, k = i & 127;
        qkvwT[(size_t)(n >> 7) * 16384 + frag_idx(n & 127, k)] = f2b(qkvw[k * 384 + n]);
        return;
    }
    i -= 384 * 128;
    if (i < 128 * 128) {             // riw [128 k][128 n]
        int n = i >> 7, k = i & 127;
        riwT[frag_idx(n, k)] = f2b(riw[k * 128 + n]);
        return;
    }
    i -= 128 * 128;
    if (i < 512 * 128) {             // fiw [128 k][512 n] -> blocks by n>>7
        int n = i >> 7, k = i & 127;
        fiwT[(size_t)(n >> 7) * 16384 + frag_idx(n & 127, k)] = f2b(fiw[k * 512 + n]);
        return;
    }
    i -= 512 * 128;
    if (i < 128 * 512) {             // fow [512 k][128 n] -> blocks by k>>7
        int n = i >> 9, k = i & 511;
        fowT[(size_t)(k >> 7) * 16384 + frag_idx(n, k & 127)] = f2b(fow[k * 128 + n]);
    }
}

// ---- K1: LN(triplet_h) @ qkv_w + b -> q8/k8/v8 (fp8 e4m3, q UNscaled) -------
__global__ __launch_bounds__(256) void k1_ln_qkv(
    const float* __restrict__ th, const float* __restrict__ g1, const float* __restrict__ b1,
    const ushort_t* __restrict__ wT, const float* __restrict__ bias,
    uchar_t* __restrict__ q8, uchar_t* __restrict__ k8, uchar_t* __restrict__ v8)
{
    __shared__ __align__(16) ushort_t xs[64][136];
    __shared__ __align__(16) ushort_t wbuf[16384];
    const int tid = threadIdx.x, lane = tid & 63, w = tid >> 6;
    const int g0 = blockIdx.x * 64;
    const bf16x8* wb8 = (const bf16x8*)wbuf;

    // stage chunk 0 weights (overlaps LN)
    #pragma unroll
    for (int t = 0; t < 8; ++t)
        gload16(wT + (size_t)(t * 256 + tid) * 8, wbuf + (t * 256 + tid) * 8);

    float ga = g1[lane], gb = g1[lane + 64];
    float ba = b1[lane], bb = b1[lane + 64];
    for (int rr = 0; rr < 16; ++rr) {
        int r = w * 16 + rr, grow = g0 + r;
        float x0 = 0.f, x1 = 0.f;
        if (grow < N_NODES) {
            x0 = th[(size_t)grow * 128 + lane];
            x1 = th[(size_t)grow * 128 + 64 + lane];
        }
        float s1 = x0 + x1, s2 = x0 * x0 + x1 * x1;
        #pragma unroll
        for (int off = 32; off; off >>= 1) { s1 += __shfl_xor(s1, off); s2 += __shfl_xor(s2, off); }
        float m = s1 * (1.f / 128.f);
        float v = s2 * (1.f / 128.f) - m * m;
        float rs = rsqrtf(v + LEPS);
        xs[r][lane]      = f2b((x0 - m) * rs * ga + ba);
        xs[r][lane + 64] = f2b((x1 - m) * rs * gb + bb);
    }
    __syncthreads();

    const int q = lane >> 4, ml = lane & 15;
    bf16x8 a[4];
    #pragma unroll
    for (int kc = 0; kc < 4; ++kc)
        a[kc] = *(const bf16x8*)&xs[w * 16 + ml][kc * 32 + q * 8];
    const int rbase = g0 + w * 16 + q * 4;

    for (int ch = 0; ch < 3; ++ch) {
        if (ch) {
            __syncthreads();
            #pragma unroll
            for (int t = 0; t < 8; ++t)
                gload16(wT + (size_t)ch * 16384 + (t * 256 + tid) * 8, wbuf + (t * 256 + tid) * 8);
            __syncthreads();
        } else {
            __syncthreads();
        }
        uchar_t* outp = (ch == 0) ? q8 : (ch == 1) ? k8 : v8;
        #pragma unroll
        for (int t2 = 0; t2 < 8; ++t2) {
            int n = t2 * 16 + ml;
            f32x4 acc = {0.f, 0.f, 0.f, 0.f};
            #pragma unroll
            for (int kc = 0; kc < 4; ++kc)
                acc = __builtin_amdgcn_mfma_f32_16x16x32_bf16(
                    a[kc], wb8[(t2 * 4 + kc) * 64 + lane], acc, 0, 0, 0);
            float bs = bias[ch * 128 + n];
            #pragma unroll
            for (int r = 0; r < 4; ++r) {
                int grow = rbase + r;
                if (grow < N_NODES)
                    outp[(size_t)grow * 128 + n] = f2fp8(acc[r] + bs);
            }
        }
    }
}

// ---- K23: fused edge-score + per-node softmax + v aggregation ---------------
// 2 nodes/block, 256 thr. Phase A: 32 (node,slot) pairs x 8 heads compute
// score = QSCALE*dot(q8[src],k8[dst]) + eb. Phase B: softmax over 16 slots, agg v.
__global__ __launch_bounds__(256) void k23_agg(
    const uchar_t* __restrict__ q8, const uchar_t* __restrict__ k8,
    const uchar_t* __restrict__ v8,
    const int* __restrict__ src, const int* __restrict__ dst,
    const int* __restrict__ inc_idx, const float* __restrict__ eb,
    ushort_t* __restrict__ outw)
{
    __shared__ int es[32];
    __shared__ int ss[32];
    __shared__ int ds[32];
    __shared__ float sc[2][16][8];
    const int tid = threadIdx.x;
    const int nb = blockIdx.x * 2;

    if (tid < 32) {
        int n = nb + (tid >> 4);
        int e = inc_idx[(size_t)n * 16 + (tid & 15)];
        if (e < 0) e = 0;
        es[tid] = e;
        ss[tid] = src[e];
        ds[tid] = dst[e];
    }
    __syncthreads();
    {
        int pair = tid >> 3, h = tid & 7;
        int e = es[pair], s = ss[pair], d = ds[pair];
        uint4 qa = *(const uint4*)(q8 + (size_t)s * 128 + h * 16);
        uint4 ka = *(const uint4*)(k8 + (size_t)d * 128 + h * 16);
        const unsigned int* qu = (const unsigned int*)&qa;
        const unsigned int* ku = (const unsigned int*)&ka;
        float acc = 0.f;
        #pragma unroll
        for (int j = 0; j < 4; ++j) {
            f32x2 q0 = __builtin_amdgcn_cvt_pk_f32_fp8(qu[j], false);
            f32x2 q1 = __builtin_amdgcn_cvt_pk_f32_fp8(qu[j], true);
            f32x2 k0 = __builtin_amdgcn_cvt_pk_f32_fp8(ku[j], false);
            f32x2 k1 = __builtin_amdgcn_cvt_pk_f32_fp8(ku[j], true);
            acc = fmaf(q0.x, k0.x, acc); acc = fmaf(q0.y, k0.y, acc);
            acc = fmaf(q1.x, k1.x, acc); acc = fmaf(q1.y, k1.y, acc);
        }
        sc[pair >> 4][pair & 15][h] = acc * QSCALE + eb[(size_t)e * 8 + h];
    }
    __syncthreads();

    const int loc = tid >> 7;
    const int j = tid & 127;   // 0..127 = h*16+dh
    const int h = j >> 4;
    float m = -1e30f;
    #pragma unroll
    for (int k = 0; k < 16; k++) m = fmaxf(m, sc[loc][k][h]);
    float p[16];
    float sum = 0.f;
    #pragma unroll
    for (int k = 0; k < 16; k++) { p[k] = __expf(sc[loc][k][h] - m); sum += p[k]; }
    float inv = 1.f / sum;
    float acc = 0.f;
    #pragma unroll
    for (int k = 0; k < 16; k++)
        acc += p[k] * __builtin_amdgcn_cvt_f32_fp8((int)v8[(size_t)ss[loc * 16 + k] * 128 + j], 0);
    outw[(size_t)(nb + loc) * 128 + j] = f2b(acc * inv);
}

// ---- K4: x2 = th + out@riw + rib; LN; FFN(gelu); out = x2 + y ---------------
__global__ __launch_bounds__(256) void k4_ffn(
    const float* __restrict__ th, const ushort_t* __restrict__ outw,
    const ushort_t* __restrict__ riwT, const float* __restrict__ rib,
    const float* __restrict__ rlg, const float* __restrict__ rlb,
    const ushort_t* __restrict__ fiwT, const float* __restrict__ fib,
    const ushort_t* __restrict__ fowT, const float* __restrict__ fob,
    float* __restrict__ dout)
{
    __shared__ __align__(16) ushort_t ys[64][136];
    __shared__ __align__(16) ushort_t hs[64][136];
    __shared__ __align__(16) ushort_t wbuf[16384];
    const int tid = threadIdx.x, lane = tid & 63, w = tid >> 6;
    const int g0 = blockIdx.x * 64;
    const int q = lane >> 4, ml = lane & 15;
    const int rloc = w * 16 + q * 4;
    const int aswz = (ml >> 2) & 3;      // read-side row swizzle for ys/hs
    const bf16x8* wb8 = (const bf16x8*)wbuf;

    // stage riw weights (DMA overlaps A-fragment loads)
    #pragma unroll
    for (int t = 0; t < 8; ++t)
        gload16(riwT + (size_t)(t * 256 + tid) * 8, wbuf + (t * 256 + tid) * 8);

    // GEMM1 A-fragments straight from global (bf16 outw, L2/L3-resident)
    int arow = g0 + w * 16 + ml; if (arow > N_NODES - 1) arow = N_NODES - 1;
    bf16x8 a[4];
    #pragma unroll
    for (int kc = 0; kc < 4; ++kc)
        a[kc] = *(const bf16x8*)(outw + (size_t)arow * 128 + kc * 32 + q * 8);
    __syncthreads();

    // GEMM1: x2 = out @ riw
    f32x4 x2[8];
    #pragma unroll
    for (int t = 0; t < 8; ++t) {
        f32x4 acc = {0.f, 0.f, 0.f, 0.f};
        #pragma unroll
        for (int kc = 0; kc < 4; ++kc)
            acc = __builtin_amdgcn_mfma_f32_16x16x32_bf16(
                a[kc], wb8[(t * 4 + kc) * 64 + lane], acc, 0, 0, 0);
        x2[t] = acc;
    }
    #pragma unroll
    for (int t = 0; t < 8; ++t) {
        float bb = rib[t * 16 + ml];
        #pragma unroll
        for (int r = 0; r < 4; ++r) {
            int grow = g0 + rloc + r;
            float tv = (grow < N_NODES) ? th[(size_t)grow * 128 + t * 16 + ml] : 0.f;
            x2[t][r] += bb + tv;
        }
    }

    // LN(x2) -> ys (bf16, swizzled); row spread over 16 ml-lanes (8 cols each)
    {
        float rg[8], rbv[8];
        #pragma unroll
        for (int t = 0; t < 8; ++t) { rg[t] = rlg[t * 16 + ml]; rbv[t] = rlb[t * 16 + ml]; }
        #pragma unroll
        for (int r = 0; r < 4; ++r) {
            float s1 = 0.f, s2 = 0.f;
            #pragma unroll
            for (int t = 0; t < 8; ++t) { float v = x2[t][r]; s1 += v; s2 += v * v; }
            #pragma unroll
            for (int off = 1; off < 16; off <<= 1) { s1 += __shfl_xor(s1, off); s2 += __shfl_xor(s2, off); }
            float m = s1 * (1.f / 128.f);
            float v = s2 * (1.f / 128.f) - m * m;
            float rs = rsqrtf(v + LEPS);
            #pragma unroll
            for (int t = 0; t < 8; ++t) {
                int G = (2 * t + (ml >> 3)) ^ q;   // (n>>2)&3 == q for rows rloc+r
                ys[rloc + r][G * 8 + (ml & 7)] = f2b((x2[t][r] - m) * rs * rg[t] + rbv[t]);
            }
        }
    }
    __syncthreads();   // ys ready; GEMM1 wbuf reads done

    bf16x8 a2[4];
    #pragma unroll
    for (int kc = 0; kc < 4; ++kc)
        a2[kc] = *(const bf16x8*)&ys[w * 16 + ml][(((kc * 4 + q) ^ aswz) << 3)];

    f32x4 y2[8];
    #pragma unroll
    for (int t = 0; t < 8; ++t) y2[t] = (f32x4){0.f, 0.f, 0.f, 0.f};

    for (int c4 = 0; c4 < 4; ++c4) {
        // stage fiw chunk (fragment-order, flat copy)
        #pragma unroll
        for (int t = 0; t < 8; ++t)
            gload16(fiwT + (size_t)c4 * 16384 + (t * 256 + tid) * 8, wbuf + (t * 256 + tid) * 8);
        __syncthreads();
        // GEMM2 chunk + gelu -> hs (swizzled)
        #pragma unroll
        for (int t2 = 0; t2 < 8; ++t2) {
            f32x4 hacc = {0.f, 0.f, 0.f, 0.f};
            #pragma unroll
            for (int kc = 0; kc < 4; ++kc)
                hacc = __builtin_amdgcn_mfma_f32_16x16x32_bf16(
                    a2[kc], wb8[(t2 * 4 + kc) * 64 + lane], hacc, 0, 0, 0);
            float fb = fib[c4 * 128 + t2 * 16 + ml];
            int G = (2 * t2 + (ml >> 3)) ^ q;
            #pragma unroll
            for (int r = 0; r < 4; ++r)
                hs[rloc + r][G * 8 + (ml & 7)] = f2b(gelu_f(hacc[r] + fb));
        }
        __syncthreads();   // hs ready + GEMM2 wbuf reads done
        // stage fow k-segment c4 (fragment-order, flat copy)
        #pragma unroll
        for (int t = 0; t < 8; ++t)
            gload16(fowT + (size_t)c4 * 16384 + (t * 256 + tid) * 8, wbuf + (t * 256 + tid) * 8);
        __syncthreads();
        // GEMM3 chunk: y2 += h @ fow_seg
        bf16x8 a3[4];
        #pragma unroll
        for (int kc = 0; kc < 4; ++kc)
            a3[kc] = *(const bf16x8*)&hs[w * 16 + ml][(((kc * 4 + q) ^ aswz) << 3)];
        #pragma unroll
        for (int t = 0; t < 8; ++t) {
            #pragma unroll
            for (int kc = 0; kc < 4; ++kc)
                y2[t] = __builtin_amdgcn_mfma_f32_16x16x32_bf16(
                    a3[kc], wb8[(t * 4 + kc) * 64 + lane], y2[t], 0, 0, 0);
        }
        __syncthreads();   // wbuf + hs free for next c4
    }

    // epilogue: out = x2 + y2 + fob
    #pragma unroll
    for (int t = 0; t < 8; ++t) {
        float ob = fob[t * 16 + ml];
        #pragma unroll
        for (int r = 0; r < 4; ++r) {
            int grow = g0 + rloc + r;
            if (grow < N_NODES)
                dout[(size_t)grow * 128 + t * 16 + ml] = x2[t][r] + y2[t][r] + ob;
        }
    }
}

extern "C" void kernel_launch(void* const* d_in, const int* in_sizes, int n_in,
                              void* d_out, int out_size, void* d_ws, size_t ws_size,
                              hipStream_t stream)
{
    const float* th    = (const float*)d_in[0];
    const int*   src   = (const int*)d_in[2];
    const int*   dst   = (const int*)d_in[3];
    const float* ebias = (const float*)d_in[4];
    const int*   inc   = (const int*)d_in[6];
    const float* ln1g  = (const float*)d_in[8];
    const float* ln1b  = (const float*)d_in[9];
    const float* qkvw  = (const float*)d_in[10];
    const float* qkvb  = (const float*)d_in[11];
    const float* riw   = (const float*)d_in[12];
    const float* rib   = (const float*)d_in[13];
    const float* rlg   = (const float*)d_in[14];
    const float* rlb   = (const float*)d_in[15];
    const float* fiw   = (const float*)d_in[16];
    const float* fib   = (const float*)d_in[17];
    const float* fow   = (const float*)d_in[18];
    const float* fob   = (const float*)d_in[19];

    char* ws = (char*)d_ws;
    uchar_t* q8      = (uchar_t*)ws;                               ws += (size_t)N_NODES * 128;
    uchar_t* k8      = (uchar_t*)ws;                               ws += (size_t)N_NODES * 128;
    uchar_t* v8      = (uchar_t*)ws;                               ws += (size_t)N_NODES * 128;
    ushort_t* outw   = (ushort_t*)ws;                              ws += (size_t)N_NODES * 128 * 2;
    ushort_t* qkvwT  = (ushort_t*)ws;                              ws += (size_t)384 * 128 * 2;
    ushort_t* riwT   = (ushort_t*)ws;                              ws += (size_t)128 * 128 * 2;
    ushort_t* fiwT   = (ushort_t*)ws;                              ws += (size_t)512 * 128 * 2;
    ushort_t* fowT   = (ushort_t*)ws;                              ws += (size_t)128 * 512 * 2;
    float* dout = (float*)d_out;

    k_prep<<<768, 256, 0, stream>>>(qkvw, riw, fiw, fow, qkvwT, riwT, fiwT, fowT);
    k1_ln_qkv<<<(N_NODES + 63) / 64, 256, 0, stream>>>(th, ln1g, ln1b, qkvwT, qkvb, q8, k8, v8);
    k23_agg<<<N_NODES / 2, 256, 0, stream>>>(q8, k8, v8, src, dst, inc, ebias, outw);
    k4_ffn<<<(N_NODES + 63) / 64, 256, 0, stream>>>(th, outw, riwT, rib, rlg, rlb,
                                                    fiwT, fib, fowT, fob, dout);
}

// Round 6
// 289.548 us; speedup vs baseline: 2.7351x; 1.0883x over previous
//
#include <hip/hip_runtime.h>
#include <math.h>

#define N_NODES 50000
#define N_EDGES 800000
#define QSCALE 0.08838834764831845f
#define LEPS 1e-5f

typedef unsigned short ushort_t;
typedef unsigned char uchar_t;
typedef short bf16x8 __attribute__((ext_vector_type(8)));
typedef float f32x4 __attribute__((ext_vector_type(4)));
typedef float f32x2 __attribute__((ext_vector_type(2)));

__device__ __forceinline__ ushort_t f2b(float f) {
    unsigned int u = __float_as_uint(f);
    u += 0x7FFF + ((u >> 16) & 1);   // RNE
    return (ushort_t)(u >> 16);
}
__device__ __forceinline__ uchar_t f2fp8(float f) {
    unsigned int pk = __builtin_amdgcn_cvt_pk_fp8_f32(f, f, 0, false);
    return (uchar_t)(pk & 0xff);
}
// fast gelu: tanh(z) = 1 - 2/(exp(2z)+1); __expf -> v_exp_f32
__device__ __forceinline__ float gelu_f(float x) {
    float u = 1.5957691216057308f * (x + 0.044715f * x * x * x);  // 2*sqrt(2/pi)*(...)
    float e = __expf(u);
    float t = 1.f - 2.f / (e + 1.f);
    return 0.5f * x * (1.f + t);
}
// async global->LDS DMA, 16B per lane (dest = wave-uniform base + lane*16)
__device__ __forceinline__ void gload16(const ushort_t* g, ushort_t* l) {
    __builtin_amdgcn_global_load_lds(
        (const __attribute__((address_space(1))) unsigned int*)g,
        (__attribute__((address_space(3))) unsigned int*)l, 16, 0, 0);
}
// fragment-order index inside a 128n x 128k bf16 block (32 KB)
__device__ __forceinline__ int frag_idx(int n7, int k7) {
    return ((n7 >> 4) * 4 + (k7 >> 5)) * 512 + ((k7 >> 3) & 3) * 128 + (n7 & 15) * 8 + (k7 & 7);
}
// fragment-order index inside a 128n x 64k bf16 block (16 KB)
__device__ __forceinline__ int fidx64(int n7, int k6) {
    return ((n7 >> 4) * 2 + (k6 >> 5)) * 512 + ((k6 >> 3) & 3) * 128 + (n7 & 15) * 8 + (k6 & 7);
}

// ---- Prep: weights -> bf16 fragment-order wave tiles ------------------------
// qkvwT: 6 blocks of 8192 (ch 0..2 x khalf 0..1). riw/fiw/fow: 32 KB blocks.
__global__ __launch_bounds__(256) void k_prep(
    const float* __restrict__ qkvw, const float* __restrict__ riw,
    const float* __restrict__ fiw,  const float* __restrict__ fow,
    ushort_t* __restrict__ qkvwT, ushort_t* __restrict__ riwT,
    ushort_t* __restrict__ fiwT,  ushort_t* __restrict__ fowT)
{
    int i = blockIdx.x * 256 + threadIdx.x;
    if (i < 384 * 128) {             // qkvw [128 k][384 n]
        int n = i >> 7, k = i & 127;
        int ch = n >> 7, n7 = n & 127, half = k >> 6, k6 = k & 63;
        qkvwT[(size_t)(ch * 2 + half) * 8192 + fidx64(n7, k6)] = f2b(qkvw[k * 384 + n]);
        return;
    }
    i -= 384 * 128;
    if (i < 128 * 128) {             // riw [128 k][128 n]
        int n = i >> 7, k = i & 127;
        riwT[frag_idx(n, k)] = f2b(riw[k * 128 + n]);
        return;
    }
    i -= 128 * 128;
    if (i < 512 * 128) {             // fiw [128 k][512 n] -> blocks by n>>7
        int n = i >> 7, k = i & 127;
        fiwT[(size_t)(n >> 7) * 16384 + frag_idx(n & 127, k)] = f2b(fiw[k * 512 + n]);
        return;
    }
    i -= 512 * 128;
    if (i < 128 * 512) {             // fow [512 k][128 n] -> blocks by k>>7
        int n = i >> 9, k = i & 511;
        fowT[(size_t)(k >> 7) * 16384 + frag_idx(n, k & 127)] = f2b(fow[k * 128 + n]);
    }
}

// ---- K1: LN(triplet_h) @ qkv_w + b -> q8/k8/v8 (fp8 e4m3, q UNscaled) -------
// 64 rows/block. 16 KB weight half-chunks; fp8 out staged via LDS. LDS ~33 KB.
__global__ __launch_bounds__(256) void k1_ln_qkv(
    const float* __restrict__ th, const float* __restrict__ g1, const float* __restrict__ b1,
    const ushort_t* __restrict__ wT, const float* __restrict__ bias,
    uchar_t* __restrict__ q8, uchar_t* __restrict__ k8, uchar_t* __restrict__ v8)
{
    __shared__ __align__(16) ushort_t xs[64][136];
    __shared__ __align__(16) ushort_t wbuf[8192];
    const int tid = threadIdx.x, lane = tid & 63, w = tid >> 6;
    const int g0 = blockIdx.x * 64;
    const bf16x8* wb8 = (const bf16x8*)wbuf;
    uchar_t* sbuf8 = (uchar_t*)xs;   // 8 KB out-staging, reused after a[] loaded

    float ga = g1[lane], gb = g1[lane + 64];
    float ba = b1[lane], bb = b1[lane + 64];
    for (int rr = 0; rr < 16; ++rr) {
        int r = w * 16 + rr, grow = g0 + r;
        float x0 = 0.f, x1 = 0.f;
        if (grow < N_NODES) {
            x0 = th[(size_t)grow * 128 + lane];
            x1 = th[(size_t)grow * 128 + 64 + lane];
        }
        float s1 = x0 + x1, s2 = x0 * x0 + x1 * x1;
        #pragma unroll
        for (int off = 32; off; off >>= 1) { s1 += __shfl_xor(s1, off); s2 += __shfl_xor(s2, off); }
        float m = s1 * (1.f / 128.f);
        float v = s2 * (1.f / 128.f) - m * m;
        float rs = rsqrtf(v + LEPS);
        xs[r][lane]      = f2b((x0 - m) * rs * ga + ba);
        xs[r][lane + 64] = f2b((x1 - m) * rs * gb + bb);
    }
    __syncthreads();

    const int q = lane >> 4, ml = lane & 15;
    const int rloc = w * 16 + q * 4;
    bf16x8 a[4];
    #pragma unroll
    for (int kc = 0; kc < 4; ++kc)
        a[kc] = *(const bf16x8*)&xs[w * 16 + ml][kc * 32 + q * 8];

    for (int ch = 0; ch < 3; ++ch) {
        f32x4 acc[8];
        #pragma unroll
        for (int t2 = 0; t2 < 8; ++t2) acc[t2] = (f32x4){0.f, 0.f, 0.f, 0.f};
        #pragma unroll
        for (int half = 0; half < 2; ++half) {
            __syncthreads();   // prior wbuf reads / sbuf8 copy-out done
            #pragma unroll
            for (int t = 0; t < 4; ++t)
                gload16(wT + (size_t)(ch * 2 + half) * 8192 + (t * 256 + tid) * 8,
                        wbuf + (t * 256 + tid) * 8);
            __syncthreads();
            #pragma unroll
            for (int t2 = 0; t2 < 8; ++t2)
                #pragma unroll
                for (int kc2 = 0; kc2 < 2; ++kc2)
                    acc[t2] = __builtin_amdgcn_mfma_f32_16x16x32_bf16(
                        a[half * 2 + kc2], wb8[(t2 * 2 + kc2) * 64 + lane], acc[t2], 0, 0, 0);
        }
        // bias + fp8 -> LDS staging
        #pragma unroll
        for (int t2 = 0; t2 < 8; ++t2) {
            int n = t2 * 16 + ml;
            float bs = bias[ch * 128 + n];
            #pragma unroll
            for (int r = 0; r < 4; ++r)
                sbuf8[(rloc + r) * 128 + n] = f2fp8(acc[t2][r] + bs);
        }
        __syncthreads();
        // coalesced copy-out: 32 B per thread
        uchar_t* outp = (ch == 0) ? q8 : (ch == 1) ? k8 : v8;
        int grow = g0 + (tid >> 2);
        if (grow < N_NODES) {
            uint4 v0 = *(const uint4*)(sbuf8 + tid * 32);
            uint4 v1 = *(const uint4*)(sbuf8 + tid * 32 + 16);
            *(uint4*)(outp + (size_t)grow * 128 + (tid & 3) * 32) = v0;
            *(uint4*)(outp + (size_t)grow * 128 + (tid & 3) * 32 + 16) = v1;
        }
    }
}

// ---- K23: fused edge-score + per-node softmax + v aggregation ---------------
__global__ __launch_bounds__(256) void k23_agg(
    const uchar_t* __restrict__ q8, const uchar_t* __restrict__ k8,
    const uchar_t* __restrict__ v8,
    const int* __restrict__ src, const int* __restrict__ dst,
    const int* __restrict__ inc_idx, const float* __restrict__ eb,
    ushort_t* __restrict__ outw)
{
    __shared__ int es[32];
    __shared__ int ss[32];
    __shared__ int ds[32];
    __shared__ float sc[2][16][8];
    const int tid = threadIdx.x;
    const int nb = blockIdx.x * 2;

    if (tid < 32) {
        int n = nb + (tid >> 4);
        int e = inc_idx[(size_t)n * 16 + (tid & 15)];
        if (e < 0) e = 0;
        es[tid] = e;
        ss[tid] = src[e];
        ds[tid] = dst[e];
    }
    __syncthreads();
    {
        int pair = tid >> 3, h = tid & 7;
        int e = es[pair], s = ss[pair], d = ds[pair];
        uint4 qa = *(const uint4*)(q8 + (size_t)s * 128 + h * 16);
        uint4 ka = *(const uint4*)(k8 + (size_t)d * 128 + h * 16);
        const unsigned int* qu = (const unsigned int*)&qa;
        const unsigned int* ku = (const unsigned int*)&ka;
        float acc = 0.f;
        #pragma unroll
        for (int j = 0; j < 4; ++j) {
            f32x2 q0 = __builtin_amdgcn_cvt_pk_f32_fp8(qu[j], false);
            f32x2 q1 = __builtin_amdgcn_cvt_pk_f32_fp8(qu[j], true);
            f32x2 k0 = __builtin_amdgcn_cvt_pk_f32_fp8(ku[j], false);
            f32x2 k1 = __builtin_amdgcn_cvt_pk_f32_fp8(ku[j], true);
            acc = fmaf(q0.x, k0.x, acc); acc = fmaf(q0.y, k0.y, acc);
            acc = fmaf(q1.x, k1.x, acc); acc = fmaf(q1.y, k1.y, acc);
        }
        sc[pair >> 4][pair & 15][h] = acc * QSCALE + eb[(size_t)e * 8 + h];
    }
    __syncthreads();

    const int loc = tid >> 7;
    const int j = tid & 127;   // 0..127 = h*16+dh
    const int h = j >> 4;
    float m = -1e30f;
    #pragma unroll
    for (int k = 0; k < 16; k++) m = fmaxf(m, sc[loc][k][h]);
    float p[16];
    float sum = 0.f;
    #pragma unroll
    for (int k = 0; k < 16; k++) { p[k] = __expf(sc[loc][k][h] - m); sum += p[k]; }
    float inv = 1.f / sum;
    float acc = 0.f;
    #pragma unroll
    for (int k = 0; k < 16; k++)
        acc += p[k] * __builtin_amdgcn_cvt_f32_fp8((int)v8[(size_t)ss[loc * 16 + k] * 128 + j], 0);
    outw[(size_t)(nb + loc) * 128 + j] = f2b(acc * inv);
}

// ---- K4: x2 = th + out@riw + rib; LN; FFN(gelu); out = x2 + y ---------------
// sbuf shared between ys and hs (a2 reg-resident before hs written). LDS ~49 KB.
__global__ __launch_bounds__(256) void k4_ffn(
    const float* __restrict__ th, const ushort_t* __restrict__ outw,
    const ushort_t* __restrict__ riwT, const float* __restrict__ rib,
    const float* __restrict__ rlg, const float* __restrict__ rlb,
    const ushort_t* __restrict__ fiwT, const float* __restrict__ fib,
    const ushort_t* __restrict__ fowT, const float* __restrict__ fob,
    float* __restrict__ dout)
{
    __shared__ __align__(16) ushort_t sbuf[64][136];   // ys then hs
    __shared__ __align__(16) ushort_t wbuf[16384];
    const int tid = threadIdx.x, lane = tid & 63, w = tid >> 6;
    const int g0 = blockIdx.x * 64;
    const int q = lane >> 4, ml = lane & 15;
    const int rloc = w * 16 + q * 4;
    const int aswz = (ml >> 2) & 3;      // read-side row swizzle for ys/hs
    const bf16x8* wb8 = (const bf16x8*)wbuf;

    // stage riw weights (DMA overlaps A-fragment loads)
    #pragma unroll
    for (int t = 0; t < 8; ++t)
        gload16(riwT + (size_t)(t * 256 + tid) * 8, wbuf + (t * 256 + tid) * 8);

    // GEMM1 A-fragments straight from global (bf16 outw, L2/L3-resident)
    int arow = g0 + w * 16 + ml; if (arow > N_NODES - 1) arow = N_NODES - 1;
    bf16x8 a[4];
    #pragma unroll
    for (int kc = 0; kc < 4; ++kc)
        a[kc] = *(const bf16x8*)(outw + (size_t)arow * 128 + kc * 32 + q * 8);
    __syncthreads();

    // GEMM1: x2 = out @ riw
    f32x4 x2[8];
    #pragma unroll
    for (int t = 0; t < 8; ++t) {
        f32x4 acc = {0.f, 0.f, 0.f, 0.f};
        #pragma unroll
        for (int kc = 0; kc < 4; ++kc)
            acc = __builtin_amdgcn_mfma_f32_16x16x32_bf16(
                a[kc], wb8[(t * 4 + kc) * 64 + lane], acc, 0, 0, 0);
        x2[t] = acc;
    }
    #pragma unroll
    for (int t = 0; t < 8; ++t) {
        float bb = rib[t * 16 + ml];
        #pragma unroll
        for (int r = 0; r < 4; ++r) {
            int grow = g0 + rloc + r;
            float tv = (grow < N_NODES) ? th[(size_t)grow * 128 + t * 16 + ml] : 0.f;
            x2[t][r] += bb + tv;
        }
    }

    // LN(x2) -> sbuf as ys (bf16, G-swizzled)
    {
        float rg[8], rbv[8];
        #pragma unroll
        for (int t = 0; t < 8; ++t) { rg[t] = rlg[t * 16 + ml]; rbv[t] = rlb[t * 16 + ml]; }
        #pragma unroll
        for (int r = 0; r < 4; ++r) {
            float s1 = 0.f, s2 = 0.f;
            #pragma unroll
            for (int t = 0; t < 8; ++t) { float v = x2[t][r]; s1 += v; s2 += v * v; }
            #pragma unroll
            for (int off = 1; off < 16; off <<= 1) { s1 += __shfl_xor(s1, off); s2 += __shfl_xor(s2, off); }
            float m = s1 * (1.f / 128.f);
            float v = s2 * (1.f / 128.f) - m * m;
            float rs = rsqrtf(v + LEPS);
            #pragma unroll
            for (int t = 0; t < 8; ++t) {
                int G = (2 * t + (ml >> 3)) ^ q;
                sbuf[rloc + r][G * 8 + (ml & 7)] = f2b((x2[t][r] - m) * rs * rg[t] + rbv[t]);
            }
        }
    }
    __syncthreads();   // ys visible (within-wave anyway); GEMM1 wbuf reads done

    bf16x8 a2[4];
    #pragma unroll
    for (int kc = 0; kc < 4; ++kc)
        a2[kc] = *(const bf16x8*)&sbuf[w * 16 + ml][(((kc * 4 + q) ^ aswz) << 3)];

    f32x4 y2[8];
    #pragma unroll
    for (int t = 0; t < 8; ++t) y2[t] = (f32x4){0.f, 0.f, 0.f, 0.f};

    for (int c4 = 0; c4 < 4; ++c4) {
        __syncthreads();   // wbuf reads (GEMM1/GEMM3) + a3 reads of prev hs done
        #pragma unroll
        for (int t = 0; t < 8; ++t)
            gload16(fiwT + (size_t)c4 * 16384 + (t * 256 + tid) * 8, wbuf + (t * 256 + tid) * 8);
        __syncthreads();
        // GEMM2 chunk + gelu -> sbuf as hs (same swizzle)
        #pragma unroll
        for (int t2 = 0; t2 < 8; ++t2) {
            f32x4 hacc = {0.f, 0.f, 0.f, 0.f};
            #pragma unroll
            for (int kc = 0; kc < 4; ++kc)
                hacc = __builtin_amdgcn_mfma_f32_16x16x32_bf16(
                    a2[kc], wb8[(t2 * 4 + kc) * 64 + lane], hacc, 0, 0, 0);
            float fb = fib[c4 * 128 + t2 * 16 + ml];
            int G = (2 * t2 + (ml >> 3)) ^ q;
            #pragma unroll
            for (int r = 0; r < 4; ++r)
                sbuf[rloc + r][G * 8 + (ml & 7)] = f2b(gelu_f(hacc[r] + fb));
        }
        __syncthreads();   // hs writes + GEMM2 wbuf reads done
        #pragma unroll
        for (int t = 0; t < 8; ++t)
            gload16(fowT + (size_t)c4 * 16384 + (t * 256 + tid) * 8, wbuf + (t * 256 + tid) * 8);
        __syncthreads();
        // GEMM3 chunk: y2 += h @ fow_seg
        bf16x8 a3[4];
        #pragma unroll
        for (int kc = 0; kc < 4; ++kc)
            a3[kc] = *(const bf16x8*)&sbuf[w * 16 + ml][(((kc * 4 + q) ^ aswz) << 3)];
        #pragma unroll
        for (int t = 0; t < 8; ++t) {
            #pragma unroll
            for (int kc = 0; kc < 4; ++kc)
                y2[t] = __builtin_amdgcn_mfma_f32_16x16x32_bf16(
                    a3[kc], wb8[(t * 4 + kc) * 64 + lane], y2[t], 0, 0, 0);
        }
    }

    // epilogue: out = x2 + y2 + fob
    #pragma unroll
    for (int t = 0; t < 8; ++t) {
        float ob = fob[t * 16 + ml];
        #pragma unroll
        for (int r = 0; r < 4; ++r) {
            int grow = g0 + rloc + r;
            if (grow < N_NODES)
                dout[(size_t)grow * 128 + t * 16 + ml] = x2[t][r] + y2[t][r] + ob;
        }
    }
}

extern "C" void kernel_launch(void* const* d_in, const int* in_sizes, int n_in,
                              void* d_out, int out_size, void* d_ws, size_t ws_size,
                              hipStream_t stream)
{
    const float* th    = (const float*)d_in[0];
    const int*   src   = (const int*)d_in[2];
    const int*   dst   = (const int*)d_in[3];
    const float* ebias = (const float*)d_in[4];
    const int*   inc   = (const int*)d_in[6];
    const float* ln1g  = (const float*)d_in[8];
    const float* ln1b  = (const float*)d_in[9];
    const float* qkvw  = (const float*)d_in[10];
    const float* qkvb  = (const float*)d_in[11];
    const float* riw   = (const float*)d_in[12];
    const float* rib   = (const float*)d_in[13];
    const float* rlg   = (const float*)d_in[14];
    const float* rlb   = (const float*)d_in[15];
    const float* fiw   = (const float*)d_in[16];
    const float* fib   = (const float*)d_in[17];
    const float* fow   = (const float*)d_in[18];
    const float* fob   = (const float*)d_in[19];

    char* ws = (char*)d_ws;
    uchar_t* q8      = (uchar_t*)ws;                               ws += (size_t)N_NODES * 128;
    uchar_t* k8      = (uchar_t*)ws;                               ws += (size_t)N_NODES * 128;
    uchar_t* v8      = (uchar_t*)ws;                               ws += (size_t)N_NODES * 128;
    ushort_t* outw   = (ushort_t*)ws;                              ws += (size_t)N_NODES * 128 * 2;
    ushort_t* qkvwT  = (ushort_t*)ws;                              ws += (size_t)384 * 128 * 2;
    ushort_t* riwT   = (ushort_t*)ws;                              ws += (size_t)128 * 128 * 2;
    ushort_t* fiwT   = (ushort_t*)ws;                              ws += (size_t)512 * 128 * 2;
    ushort_t* fowT   = (ushort_t*)ws;                              ws += (size_t)128 * 512 * 2;
    float* dout = (float*)d_out;

    k_prep<<<768, 256, 0, stream>>>(qkvw, riw, fiw, fow, qkvwT, riwT, fiwT, fowT);
    k1_ln_qkv<<<(N_NODES + 63) / 64, 256, 0, stream>>>(th, ln1g, ln1b, qkvwT, qkvb, q8, k8, v8);
    k23_agg<<<N_NODES / 2, 256, 0, stream>>>(q8, k8, v8, src, dst, inc, ebias, outw);
    k4_ffn<<<(N_NODES + 63) / 64, 256, 0, stream>>>(th, outw, riwT, rib, rlg, rlb,
                                                    fiwT, fib, fowT, fob, dout);
}